// Round 14
// baseline (99.491 us; speedup 1.0000x reference)
//
#include <hip/hip_runtime.h>
#include <hip/hip_bf16.h>

#define NCAT 16
#define BCAT 32   // blocks per category in k_main

typedef __attribute__((ext_vector_type(8))) short short8v;
typedef __attribute__((ext_vector_type(4))) float float4v;
typedef __attribute__((ext_vector_type(16))) float f32x16;

__constant__ int c_shift[NCAT] = {0,4,6,8,12,16,19,22,24,28,34,36,42,45,48,51};
__constant__ int c_len[NCAT]   = {4,2,2,4,4,3,3,2,4,6,2,6,3,3,3,3};

// ws layout (bytes):
//   sv      @ 0        (128 f32)   -> 512
//   counts  @ 512      (16 i32)    -> 576
//   blkcnt  @ 576      (256*16)    -> 16960
//   offs    @ 16960    (256*16)    -> 33344
//   scale   @ 33344    (2048 f32)  -> 41536
//   shiftv  @ 41536    (2048 f32)  -> 49728
//   G       @ 49728    (16384 f32) -> 115264
//   rowidx  @ 115264   (65536 i32) -> 377408
//   posidx  @ 377408   (65536 i32) -> 639552
//   Wlb     @ 639552   (512 KB)    -> 1163840
//   W2p     @ 1163840  (64 KB)     -> 1229376
//   tmp8    @ 1229376  (2 MB)      -> 3326528
//   Gp16    @ 3326528  (8 MB)      -> 11715136
//   svpart  @ 11715136 (128 KB)    -> 11846208   need ~11.85 MB

static inline __device__ unsigned pk2(float lo, float hi) {
  float2 f2; f2.x = lo; f2.y = hi;
  __hip_bfloat162 h = __float22bfloat162_rn(f2);
  unsigned u; __builtin_memcpy(&u, &h, 4);
  return u;
}
static inline __device__ float bf2f(unsigned short v) {
  unsigned u = (unsigned)v << 16;
  float f; __builtin_memcpy(&f, &u, 4);
  return f;
}

// ---------------------------------------------------------------------------
// K1: blocks 0..255 = MFMA Gram (256 rows, 16 waves, 32x32 tiles, bf16
// partials) + label histogram -> blkcnt. Blocks 256..271 = W1 pre-swizzle
// into MFMA B-frag layout + padded W2p table (one cat per block).
// ---------------------------------------------------------------------------
template<bool PART>
__global__ __launch_bounds__(1024) void k_stats_m(
    const float* __restrict__ F, const float* __restrict__ W1,
    const float* __restrict__ W2, const int* __restrict__ lab,
    float* __restrict__ Gdst, unsigned* __restrict__ Gp16,
    float* __restrict__ sv, float* __restrict__ svpart,
    int* __restrict__ blkcnt, unsigned short* __restrict__ Wlb,
    float* __restrict__ W2p)
{
  const int tid = threadIdx.x;
  if (blockIdx.x >= 256) {
    const int cat = (int)blockIdx.x - 256;
    for (int e = tid; e < 2048; e += 1024) {
      const int fid = e >> 6, l = e & 63;
      const int ks = fid >> 3, ct = fid & 7;
      const int kb = 32 * ks + 8 * (l >> 4);
      const int c = cat * 128 + 16 * ct + (l & 15);
      uint4 pk;
      pk.x = pk2(W1[(size_t)(kb + 0) * 2048 + c], W1[(size_t)(kb + 1) * 2048 + c]);
      pk.y = pk2(W1[(size_t)(kb + 2) * 2048 + c], W1[(size_t)(kb + 3) * 2048 + c]);
      pk.z = pk2(W1[(size_t)(kb + 4) * 2048 + c], W1[(size_t)(kb + 5) * 2048 + c]);
      pk.w = pk2(W1[(size_t)(kb + 6) * 2048 + c], W1[(size_t)(kb + 7) * 2048 + c]);
      *(uint4*)(Wlb + ((size_t)(cat * 32 + fid) * 64 + l) * 8) = pk;
    }
    if (tid < 1024) {
      const int c = tid >> 3, s = tid & 7;
      W2p[cat * 1024 + tid] = (s < 6) ? W2[cat * 768 + c * 6 + s] : 0.f;
    }
    return;
  }

  __shared__ int hl[NCAT];
  if (tid < NCAT) hl[tid] = 0;
  __syncthreads();
  const int rowbase = blockIdx.x * 256;
  if (tid < 256) atomicAdd(&hl[lab[rowbase + tid]], 1);

  const int wid = tid >> 6, lane = tid & 63;
  const int wi = wid >> 2, wj = wid & 3;
  const int i0 = wi * 32, j0 = wj * 32;
  const int lr = lane & 31, lh = lane >> 5;

  f32x16 acc;
  #pragma unroll
  for (int e = 0; e < 16; ++e) acc[e] = 0.f;
  float svacc = 0.f;

  for (int ch = 0; ch < 8; ++ch) {
    #pragma unroll
    for (int h = 0; h < 2; ++h) {
      const int rbase = rowbase + ch * 32 + 16 * h + 8 * lh;
      float fa[8], fb[8];
      #pragma unroll
      for (int j = 0; j < 8; ++j) {
        const float* rp = F + (size_t)(rbase + j) * 128;
        fa[j] = rp[i0 + lr];
        fb[j] = rp[j0 + lr];
      }
      if (wj == 0) {
        #pragma unroll
        for (int j = 0; j < 8; ++j) svacc += fa[j];
      }
      uint4 av4, bv4;
      av4.x = pk2(fa[0], fa[1]); av4.y = pk2(fa[2], fa[3]);
      av4.z = pk2(fa[4], fa[5]); av4.w = pk2(fa[6], fa[7]);
      bv4.x = pk2(fb[0], fb[1]); bv4.y = pk2(fb[2], fb[3]);
      bv4.z = pk2(fb[4], fb[5]); bv4.w = pk2(fb[6], fb[7]);
      acc = __builtin_amdgcn_mfma_f32_32x32x16_bf16(
          __builtin_bit_cast(short8v, av4), __builtin_bit_cast(short8v, bv4),
          acc, 0, 0, 0);
    }
  }

  if (wj == 0) {
    svacc += __shfl_xor(svacc, 32);
    if (lane < 32) {
      if (PART) svpart[blockIdx.x * 128 + i0 + lr] = svacc;
      else      atomicAdd(&sv[i0 + lr], svacc);
    }
  }
  __syncthreads();
  if (tid < NCAT) blkcnt[blockIdx.x * NCAT + tid] = hl[tid];

  if (PART) {
    unsigned* gp = Gp16 + (size_t)blockIdx.x * 8192;
    #pragma unroll
    for (int t = 0; t < 8; ++t) {
      const int rowe = ((2 * t) & 3) + 8 * (t >> 1) + 4 * lh;   // even row of pair
      gp[((i0 + rowe) >> 1) * 128 + j0 + lr] = pk2(acc[2 * t], acc[2 * t + 1]);
    }
  } else {
    #pragma unroll
    for (int reg = 0; reg < 16; ++reg) {
      const int row = (reg & 3) + 8 * (reg >> 2) + 4 * lh;
      atomicAdd(&Gdst[(i0 + row) * 128 + j0 + lr], acc[reg]);
    }
  }
}

// ---------------------------------------------------------------------------
// K2 (fused): b<32 G-reduce (bf16 pairs); b==32 sv-reduce; b==33 prefix sums
// over blkcnt -> offs + counts. grid 34 x 256.
// ---------------------------------------------------------------------------
__global__ __launch_bounds__(256) void k_mid(
    const unsigned* __restrict__ Gp16, const float* __restrict__ svpart,
    const int* __restrict__ blkcnt, float* __restrict__ G,
    float* __restrict__ sv, int* __restrict__ offs,
    int* __restrict__ counts, int doRed)
{
  __shared__ int ps[16][16], ps2[16][16], tot[16], catbase[16];
  const int b = blockIdx.x, tid = threadIdx.x;
  if (b < 32) {
    if (!doRed) return;
    const int e = b * 256 + tid;           // pair index 0..8191
    float lo = 0.f, hi = 0.f;
    #pragma unroll 4
    for (int p = 0; p < 256; ++p) {
      const unsigned u = Gp16[(size_t)p * 8192 + e];
      lo += bf2f((unsigned short)(u & 0xffffu));
      hi += bf2f((unsigned short)(u >> 16));
    }
    const int pr = e >> 7, col = e & 127;
    G[(2 * pr) * 128 + col]     = lo;
    G[(2 * pr + 1) * 128 + col] = hi;
  } else if (b == 32) {
    if (!doRed) return;
    if (tid < 128) {
      float s = 0.f;
      #pragma unroll 8
      for (int p = 0; p < 256; ++p) s += svpart[p * 128 + tid];
      sv[tid] = s;
    }
  } else {
    const int part = tid >> 4, cat = tid & 15;
    int v[16]; int s = 0;
    #pragma unroll
    for (int i = 0; i < 16; ++i) { v[i] = s; s += blkcnt[(part * 16 + i) * 16 + cat]; }
    ps[part][cat] = s;
    __syncthreads();
    if (part == 0) {
      int a = 0;
      #pragma unroll
      for (int p = 0; p < 16; ++p) { ps2[p][cat] = a; a += ps[p][cat]; }
      tot[cat] = a; counts[cat] = a;
    }
    __syncthreads();
    if (tid == 0) {
      int a = 0;
      #pragma unroll
      for (int c = 0; c < 16; ++c) { catbase[c] = a; a += tot[c]; }
    }
    __syncthreads();
    const int base = catbase[cat] + ps2[part][cat];
    #pragma unroll
    for (int i = 0; i < 16; ++i) offs[(part * 16 + i) * 16 + cat] = base + v[i];
  }
}

// ---------------------------------------------------------------------------
// K3 (fused): b<256 scatter (rowidx + posidx, atomic-free, deterministic);
// b>=256 BN params from Gram. grid 384 x 256.
// ---------------------------------------------------------------------------
__global__ __launch_bounds__(256) void k_prep(
    const int* __restrict__ lab, const int* __restrict__ offs,
    const float* __restrict__ G, const float* __restrict__ sv,
    const float* __restrict__ W1, const float* __restrict__ gamma,
    const float* __restrict__ beta,
    int* __restrict__ rowidx, int* __restrict__ posidx,
    float* __restrict__ scale, float* __restrict__ shiftv)
{
  __shared__ float Gl[128][133];
  __shared__ float Wl[128][16];
  __shared__ float redq[16][16];
  __shared__ float redm[16][16];
  __shared__ int wc[4][NCAT];
  const int b = blockIdx.x, tid = threadIdx.x;
  if (b < 256) {
    const int wid = tid >> 6, lane = tid & 63;
    const int n = b * 256 + tid;
    const int c = lab[n];
    const unsigned long long lanebit = 1ull << lane;
    int myrank = 0;
    #pragma unroll
    for (int cc = 0; cc < NCAT; ++cc) {
      unsigned long long m = __ballot(c == cc);
      if (lane == 0) wc[wid][cc] = (int)__popcll(m);
      if (c == cc) myrank = (int)__popcll(m & (lanebit - 1));
    }
    __syncthreads();
    int base = 0;
    #pragma unroll
    for (int w = 0; w < 4; ++w)
      if (w < wid) base += wc[w][c];
    const int slot = offs[b * NCAT + c] + base + myrank;
    rowidx[slot] = n;
    posidx[n] = slot;
  } else {
    const int jb = (b - 256) * 16;
    for (int i = tid; i < 16384; i += 256) Gl[i >> 7][i & 127] = G[i];
    for (int i = tid; i < 2048; i += 256) {
      int k = i >> 4, col = i & 15;
      Wl[k][col] = W1[(size_t)k * 2048 + jb + col];
    }
    __syncthreads();
    const int col = tid & 15, part = tid >> 4;
    float msq = 0.f, mean = 0.f;
    for (int ii = 0; ii < 8; ++ii) {
      const int i = part * 8 + ii;
      const float wi = Wl[i][col];
      float inner = 0.f;
      #pragma unroll 8
      for (int k = 0; k < 128; ++k) inner = fmaf(Gl[i][k], Wl[k][col], inner);
      msq = fmaf(wi, inner, msq);
    }
    #pragma unroll
    for (int kk = 0; kk < 8; ++kk) {
      const int k = part * 8 + kk;
      mean = fmaf(sv[k], Wl[k][col], mean);
    }
    redq[part][col] = msq;
    redm[part][col] = mean;
    __syncthreads();
    if (tid < 16) {
      float q = 0.f, m = 0.f;
      #pragma unroll
      for (int p = 0; p < 16; ++p) { q += redq[p][tid]; m += redm[p][tid]; }
      m *= (1.f / 65536.f);
      q *= (1.f / 65536.f);
      float var = q - m * m;
      float sc = gamma[jb + tid] * rsqrtf(var + 1e-5f);
      scale[jb + tid] = sc;
      shiftv[jb + tid] = beta[jb + tid] - m * sc;
    }
  }
}

// ---------------------------------------------------------------------------
// K4: category-major MFMA main. grid = 16 cat x BCAT(32); 512 thr = 8 waves.
// Block stages its category's 32 KB W tile into LDS ONCE; per group the MFMA
// loop is 32x ds_read_b128 + 32x MFMA — zero global latency in the loop.
// ~1 group of 16 rows per wave (100% fill via global sort). A-frags
// prefetched before the stage barrier. 32-B record per row -> tmp8 at slot
// position (block-contiguous streaming stores).
// ---------------------------------------------------------------------------
__global__ __launch_bounds__(512) void k_main(
    const float* __restrict__ F, const unsigned short* __restrict__ Wlb,
    const float* __restrict__ W2p, const float* __restrict__ bias,
    const float* __restrict__ scale, const float* __restrict__ shiftv,
    const int* __restrict__ counts, const int* __restrict__ rowidx,
    float* __restrict__ tmp8)
{
  __shared__ __attribute__((aligned(16))) unsigned short Wl[16384];  // 32 KB
  const int tid = threadIdx.x;
  const int cat = (int)blockIdx.x >> 5;
  const int blk = (int)blockIdx.x & (BCAT - 1);
  const int wid = tid >> 6, lane = tid & 63;
  const int lrow = lane & 15, lhi = lane >> 4;

  int off = 0, cnt = 0;
  #pragma unroll
  for (int t = 0; t < NCAT; ++t) {
    int cv = counts[t];
    if (t < cat) off += cv;
    if (t == cat) cnt = cv;
  }
  const int chunk = (cnt + BCAT - 1) / BCAT;
  const int start = off + blk * chunk;
  const int end = min(start + chunk, off + cnt);

  float sc_r[8], sh_r[8];
  #pragma unroll
  for (int ct = 0; ct < 8; ++ct) {
    sc_r[ct] = scale[cat * 128 + ct * 16 + lrow];
    sh_r[ct] = shiftv[cat * 128 + ct * 16 + lrow];
  }
  float bi[6];
  #pragma unroll
  for (int s = 0; s < 6; ++s) bi[s] = bias[s];

  // prefetch first group's A rows (before the stage barrier)
  float4 cA[4], cB[4];
  const int q00 = start + wid * 16;
  if (q00 < end) {
    const int rA = rowidx[min(q00 + lrow, end - 1)];
    const float* fp = F + (size_t)rA * 128 + lhi * 8;
    #pragma unroll
    for (int ks = 0; ks < 4; ++ks) {
      cA[ks] = *(const float4*)(fp + ks * 32);
      cB[ks] = *(const float4*)(fp + ks * 32 + 4);
    }
  }

  // stage this category's W tile into LDS (coalesced)
  {
    const uint4* src = (const uint4*)(Wlb + (size_t)cat * 16384);
    uint4* dst = (uint4*)Wl;
    for (int i = tid; i < 2048; i += 512) dst[i] = src[i];
  }
  __syncthreads();

  for (int q0 = q00; q0 < end; q0 += 8 * 16) {
    // prefetch next group's A rows (overlaps MFMA+epilogue)
    const int qn = q0 + 8 * 16;
    const bool hn = qn < end;
    float4 nA[4], nB[4];
    if (hn) {
      const int rAn = rowidx[min(qn + lrow, end - 1)];
      const float* fpn = F + (size_t)rAn * 128 + lhi * 8;
      #pragma unroll
      for (int ks = 0; ks < 4; ++ks) {
        nA[ks] = *(const float4*)(fpn + ks * 32);
        nB[ks] = *(const float4*)(fpn + ks * 32 + 4);
      }
    }

    float4v acc[8];
    #pragma unroll
    for (int ct = 0; ct < 8; ++ct) acc[ct] = (float4v){0.f, 0.f, 0.f, 0.f};

    #pragma unroll
    for (int ks = 0; ks < 4; ++ks) {
      uint4 av4;
      av4.x = pk2(cA[ks].x, cA[ks].y); av4.y = pk2(cA[ks].z, cA[ks].w);
      av4.z = pk2(cB[ks].x, cB[ks].y); av4.w = pk2(cB[ks].z, cB[ks].w);
      const short8v av = __builtin_bit_cast(short8v, av4);
      #pragma unroll
      for (int ct = 0; ct < 8; ++ct) {
        const short8v bv = *(const short8v*)(Wl + ((ks * 8 + ct) * 64 + lane) * 8);
        acc[ct] = __builtin_amdgcn_mfma_f32_16x16x32_bf16(av, bv, acc[ct], 0, 0, 0);
      }
    }

    // BN + leaky + W2 partials (lane col c = 16ct+lrow; rows 4*lhi+j)
    float p[4][6];
    #pragma unroll
    for (int j = 0; j < 4; ++j)
      #pragma unroll
      for (int s = 0; s < 6; ++s) p[j][s] = 0.f;
    #pragma unroll
    for (int ct = 0; ct < 8; ++ct) {
      const int c = ct * 16 + lrow;
      const float s_ = sc_r[ct], h_ = sh_r[ct];
      const float4* w2p4 = (const float4*)(W2p + ((size_t)cat * 128 + c) * 8);
      const float4 wa = w2p4[0];
      const float4 wb4 = w2p4[1];
      const float w2v[6] = {wa.x, wa.y, wa.z, wa.w, wb4.x, wb4.y};
      #pragma unroll
      for (int j = 0; j < 4; ++j) {
        float a = acc[ct][j] * s_ + h_;
        a = (a >= 0.f) ? a : 0.2f * a;
        #pragma unroll
        for (int s = 0; s < 6; ++s) p[j][s] = fmaf(a, w2v[s], p[j][s]);
      }
    }
    // reduce-scatter over the 16-lane group: lvl1/2 keep j == lrow&3
    const bool b1 = (lrow & 1) != 0;
    const bool b2 = (lrow & 2) != 0;
    float q[2][6], r[6];
    #pragma unroll
    for (int t = 0; t < 2; ++t)
      #pragma unroll
      for (int s = 0; s < 6; ++s) {
        float snd = b1 ? p[2 * t][s] : p[2 * t + 1][s];
        float kp  = b1 ? p[2 * t + 1][s] : p[2 * t][s];
        q[t][s] = kp + __shfl_xor(snd, 1);
      }
    #pragma unroll
    for (int s = 0; s < 6; ++s) {
      float snd = b2 ? q[0][s] : q[1][s];
      float kp  = b2 ? q[1][s] : q[0][s];
      r[s] = kp + __shfl_xor(snd, 2);
    }
    #pragma unroll
    for (int s = 0; s < 6; ++s) r[s] += __shfl_xor(r[s], 4);
    #pragma unroll
    for (int s = 0; s < 6; ++s) r[s] += __shfl_xor(r[s], 8);

    const int jj = lrow & 3, sb = lrow >> 2;
    const int qrow = min(q0 + 4 * lhi + jj, end - 1);   // slot position
    float pj[6];
    #pragma unroll
    for (int s = 0; s < 6; ++s) pj[s] = r[s] + bi[s];
    float mx = fmaxf(fmaxf(fmaxf(pj[0], pj[1]), fmaxf(pj[2], pj[3])), fmaxf(pj[4], pj[5]));
    float e = __expf(pj[0] - mx) + __expf(pj[1] - mx) + __expf(pj[2] - mx)
            + __expf(pj[3] - mx) + __expf(pj[4] - mx) + __expf(pj[5] - mx);
    float lse = mx + __logf(e);

    float4* trec = (float4*)(tmp8 + (size_t)qrow * 8);
    if (sb == 0) {
      float4 v0; v0.x = pj[0] - lse; v0.y = pj[1] - lse;
      v0.z = pj[2] - lse; v0.w = pj[3] - lse;
      trec[0] = v0;
    } else if (sb == 1) {
      float4 v1; v1.x = pj[4] - lse; v1.y = pj[5] - lse;
      v1.z = 0.f; v1.w = 0.f;
      trec[1] = v1;
    }

    if (hn) {
      #pragma unroll
      for (int ks = 0; ks < 4; ++ks) { cA[ks] = nA[ks]; cB[ks] = nB[ks]; }
    }
  }
}

// ---------------------------------------------------------------------------
// K5: permute records -> dense output in OUTPUT order (fully coalesced
// full-line stores, no RMW). grid 6912 x 256 (one float2/thread).
// ---------------------------------------------------------------------------
__global__ __launch_bounds__(256) void k_out(
    const float* __restrict__ tmp8, const int* __restrict__ lab,
    const int* __restrict__ posidx, float* __restrict__ out)
{
  const int i2 = blockIdx.x * 256 + threadIdx.x;  // 0 .. 65536*27
  const int n = i2 / 27;
  const int j2 = i2 - n * 27;
  const int c = lab[n];
  const int shc = c_shift[c], lnc = c_len[c];
  const float* rec = tmp8 + (size_t)posidx[n] * 8;
  const int s0 = 2 * j2 - shc;
  float2 v; v.x = 0.f; v.y = 0.f;
  if (s0 >= 0 && s0 < lnc)         v.x = rec[s0];
  if (s0 + 1 >= 0 && s0 + 1 < lnc) v.y = rec[s0 + 1];
  ((float2*)out)[i2] = v;
}

// ---------------------------------------------------------------------------
// Host launcher — 5 launches (fast path).
// ---------------------------------------------------------------------------
extern "C" void kernel_launch(void* const* d_in, const int* in_sizes, int n_in,
                              void* d_out, int out_size, void* d_ws, size_t ws_size,
                              hipStream_t stream) {
  const float* F     = (const float*)d_in[0];
  const float* W1    = (const float*)d_in[1];
  const float* gamma = (const float*)d_in[2];
  const float* beta  = (const float*)d_in[3];
  const float* W2    = (const float*)d_in[4];
  const float* bias  = (const float*)d_in[5];
  const int*   lab   = (const int*)d_in[6];
  float* out = (float*)d_out;

  char* ws = (char*)d_ws;
  float* sv      = (float*)(ws + 0);
  int*   counts  = (int*)(ws + 512);
  int*   blkcnt  = (int*)(ws + 576);
  int*   offs    = (int*)(ws + 16960);
  float* scale   = (float*)(ws + 33344);
  float* shiftv  = (float*)(ws + 41536);
  float* G       = (float*)(ws + 49728);
  int*   rowidx  = (int*)(ws + 115264);
  int*   posidx  = (int*)(ws + 377408);
  unsigned short* Wlb = (unsigned short*)(ws + 639552);
  float* W2p     = (float*)(ws + 1163840);
  float* tmp8    = (float*)(ws + 1229376);
  unsigned* Gp16 = (unsigned*)(ws + 3326528);
  float* svpart  = (float*)(ws + 11715136);

  const size_t need = 11846208;  // ~11.85 MB (well under proven 17.3 MB)
  const int fast = (ws_size >= need) ? 1 : 0;
  if (fast) {
    hipLaunchKernelGGL(k_stats_m<true>, dim3(272), dim3(1024), 0, stream,
                       F, W1, W2, lab, G, Gp16, sv, svpart, blkcnt, Wlb, W2p);
  } else {
    hipMemsetAsync(d_ws, 0, 115264, stream);  // sv + G (+counts/blkcnt harmless)
    hipLaunchKernelGGL(k_stats_m<false>, dim3(272), dim3(1024), 0, stream,
                       F, W1, W2, lab, G, Gp16, sv, svpart, blkcnt, Wlb, W2p);
  }
  hipLaunchKernelGGL(k_mid, dim3(34), dim3(256), 0, stream,
                     Gp16, svpart, blkcnt, G, sv, offs, counts, fast);
  hipLaunchKernelGGL(k_prep, dim3(384), dim3(256), 0, stream,
                     lab, offs, G, sv, W1, gamma, beta, rowidx, posidx, scale, shiftv);
  hipLaunchKernelGGL(k_main, dim3(NCAT * BCAT), dim3(512), 0, stream,
                     F, Wlb, W2p, bias, scale, shiftv, counts, rowidx, tmp8);
  hipLaunchKernelGGL(k_out, dim3(6912), dim3(256), 0, stream,
                     tmp8, lab, posidx, out);
}

// Round 15
// 89.690 us; speedup vs baseline: 1.1093x; 1.1093x over previous
//
#include <hip/hip_runtime.h>
#include <hip/hip_bf16.h>

#define NCAT 16
#define BCAT 32   // blocks per category in k_main

typedef __attribute__((ext_vector_type(8))) short short8v;
typedef __attribute__((ext_vector_type(4))) float float4v;
typedef __attribute__((ext_vector_type(16))) float f32x16;

__constant__ int c_shift[NCAT] = {0,4,6,8,12,16,19,22,24,28,34,36,42,45,48,51};
__constant__ int c_len[NCAT]   = {4,2,2,4,4,3,3,2,4,6,2,6,3,3,3,3};

// ws layout (bytes):
//   sv      @ 0        (128 f32)   -> 512
//   counts  @ 512      (16 i32)    -> 576
//   blkcnt  @ 576      (256*16)    -> 16960
//   offs    @ 16960    (256*16)    -> 33344
//   scale   @ 33344    (2048 f32)  -> 41536
//   shiftv  @ 41536    (2048 f32)  -> 49728
//   G       @ 49728    (16384 f32) -> 115264
//   rowidx  @ 115264   (65536 i32) -> 377408
//   posidx  @ 377408   (65536 i32) -> 639552
//   Wlb     @ 639552   (512 KB)    -> 1163840
//   W2p     @ 1163840  (64 KB)     -> 1229376
//   tmp8    @ 1229376  (2 MB)      -> 3326528
//   Gp16    @ 3326528  (8 MB)      -> 11715136  [dead after k_mid]
//   svpart  @ 11715136 (128 KB)    -> 11846208  [dead after k_mid]
//   Fsrt    @ 3326528  (16.78 MB, overlays Gp16+svpart; written by k_prep
//                       AFTER k_mid consumed them) -> 20103744  need ~20.1 MB

static inline __device__ unsigned pk2(float lo, float hi) {
  float2 f2; f2.x = lo; f2.y = hi;
  __hip_bfloat162 h = __float22bfloat162_rn(f2);
  unsigned u; __builtin_memcpy(&u, &h, 4);
  return u;
}
static inline __device__ float bf2f(unsigned short v) {
  unsigned u = (unsigned)v << 16;
  float f; __builtin_memcpy(&f, &u, 4);
  return f;
}

// ---------------------------------------------------------------------------
// K1: blocks 0..255 = MFMA Gram (256 rows, 16 waves, 32x32 tiles, bf16
// partials) + label histogram -> blkcnt. Blocks 256..271 = W1 pre-swizzle
// into MFMA B-frag layout + padded W2p table (one cat per block).
// ---------------------------------------------------------------------------
template<bool PART>
__global__ __launch_bounds__(1024) void k_stats_m(
    const float* __restrict__ F, const float* __restrict__ W1,
    const float* __restrict__ W2, const int* __restrict__ lab,
    float* __restrict__ Gdst, unsigned* __restrict__ Gp16,
    float* __restrict__ sv, float* __restrict__ svpart,
    int* __restrict__ blkcnt, unsigned short* __restrict__ Wlb,
    float* __restrict__ W2p)
{
  const int tid = threadIdx.x;
  if (blockIdx.x >= 256) {
    const int cat = (int)blockIdx.x - 256;
    for (int e = tid; e < 2048; e += 1024) {
      const int fid = e >> 6, l = e & 63;
      const int ks = fid >> 3, ct = fid & 7;
      const int kb = 32 * ks + 8 * (l >> 4);
      const int c = cat * 128 + 16 * ct + (l & 15);
      uint4 pk;
      pk.x = pk2(W1[(size_t)(kb + 0) * 2048 + c], W1[(size_t)(kb + 1) * 2048 + c]);
      pk.y = pk2(W1[(size_t)(kb + 2) * 2048 + c], W1[(size_t)(kb + 3) * 2048 + c]);
      pk.z = pk2(W1[(size_t)(kb + 4) * 2048 + c], W1[(size_t)(kb + 5) * 2048 + c]);
      pk.w = pk2(W1[(size_t)(kb + 6) * 2048 + c], W1[(size_t)(kb + 7) * 2048 + c]);
      *(uint4*)(Wlb + ((size_t)(cat * 32 + fid) * 64 + l) * 8) = pk;
    }
    if (tid < 1024) {
      const int c = tid >> 3, s = tid & 7;
      W2p[cat * 1024 + tid] = (s < 6) ? W2[cat * 768 + c * 6 + s] : 0.f;
    }
    return;
  }

  __shared__ int hl[NCAT];
  if (tid < NCAT) hl[tid] = 0;
  __syncthreads();
  const int rowbase = blockIdx.x * 256;
  if (tid < 256) atomicAdd(&hl[lab[rowbase + tid]], 1);

  const int wid = tid >> 6, lane = tid & 63;
  const int wi = wid >> 2, wj = wid & 3;
  const int i0 = wi * 32, j0 = wj * 32;
  const int lr = lane & 31, lh = lane >> 5;

  f32x16 acc;
  #pragma unroll
  for (int e = 0; e < 16; ++e) acc[e] = 0.f;
  float svacc = 0.f;

  for (int ch = 0; ch < 8; ++ch) {
    #pragma unroll
    for (int h = 0; h < 2; ++h) {
      const int rbase = rowbase + ch * 32 + 16 * h + 8 * lh;
      float fa[8], fb[8];
      #pragma unroll
      for (int j = 0; j < 8; ++j) {
        const float* rp = F + (size_t)(rbase + j) * 128;
        fa[j] = rp[i0 + lr];
        fb[j] = rp[j0 + lr];
      }
      if (wj == 0) {
        #pragma unroll
        for (int j = 0; j < 8; ++j) svacc += fa[j];
      }
      uint4 av4, bv4;
      av4.x = pk2(fa[0], fa[1]); av4.y = pk2(fa[2], fa[3]);
      av4.z = pk2(fa[4], fa[5]); av4.w = pk2(fa[6], fa[7]);
      bv4.x = pk2(fb[0], fb[1]); bv4.y = pk2(fb[2], fb[3]);
      bv4.z = pk2(fb[4], fb[5]); bv4.w = pk2(fb[6], fb[7]);
      acc = __builtin_amdgcn_mfma_f32_32x32x16_bf16(
          __builtin_bit_cast(short8v, av4), __builtin_bit_cast(short8v, bv4),
          acc, 0, 0, 0);
    }
  }

  if (wj == 0) {
    svacc += __shfl_xor(svacc, 32);
    if (lane < 32) {
      if (PART) svpart[blockIdx.x * 128 + i0 + lr] = svacc;
      else      atomicAdd(&sv[i0 + lr], svacc);
    }
  }
  __syncthreads();
  if (tid < NCAT) blkcnt[blockIdx.x * NCAT + tid] = hl[tid];

  if (PART) {
    unsigned* gp = Gp16 + (size_t)blockIdx.x * 8192;
    #pragma unroll
    for (int t = 0; t < 8; ++t) {
      const int rowe = ((2 * t) & 3) + 8 * (t >> 1) + 4 * lh;   // even row of pair
      gp[((i0 + rowe) >> 1) * 128 + j0 + lr] = pk2(acc[2 * t], acc[2 * t + 1]);
    }
  } else {
    #pragma unroll
    for (int reg = 0; reg < 16; ++reg) {
      const int row = (reg & 3) + 8 * (reg >> 2) + 4 * lh;
      atomicAdd(&Gdst[(i0 + row) * 128 + j0 + lr], acc[reg]);
    }
  }
}

// ---------------------------------------------------------------------------
// K2 (fused): b<32 G-reduce (bf16 pairs); b==32 sv-reduce; b==33 prefix sums
// over blkcnt -> offs + counts. grid 34 x 256.
// ---------------------------------------------------------------------------
__global__ __launch_bounds__(256) void k_mid(
    const unsigned* __restrict__ Gp16, const float* __restrict__ svpart,
    const int* __restrict__ blkcnt, float* __restrict__ G,
    float* __restrict__ sv, int* __restrict__ offs,
    int* __restrict__ counts, int doRed)
{
  __shared__ int ps[16][16], ps2[16][16], tot[16], catbase[16];
  const int b = blockIdx.x, tid = threadIdx.x;
  if (b < 32) {
    if (!doRed) return;
    const int e = b * 256 + tid;           // pair index 0..8191
    float lo = 0.f, hi = 0.f;
    #pragma unroll 4
    for (int p = 0; p < 256; ++p) {
      const unsigned u = Gp16[(size_t)p * 8192 + e];
      lo += bf2f((unsigned short)(u & 0xffffu));
      hi += bf2f((unsigned short)(u >> 16));
    }
    const int pr = e >> 7, col = e & 127;
    G[(2 * pr) * 128 + col]     = lo;
    G[(2 * pr + 1) * 128 + col] = hi;
  } else if (b == 32) {
    if (!doRed) return;
    if (tid < 128) {
      float s = 0.f;
      #pragma unroll 8
      for (int p = 0; p < 256; ++p) s += svpart[p * 128 + tid];
      sv[tid] = s;
    }
  } else {
    const int part = tid >> 4, cat = tid & 15;
    int v[16]; int s = 0;
    #pragma unroll
    for (int i = 0; i < 16; ++i) { v[i] = s; s += blkcnt[(part * 16 + i) * 16 + cat]; }
    ps[part][cat] = s;
    __syncthreads();
    if (part == 0) {
      int a = 0;
      #pragma unroll
      for (int p = 0; p < 16; ++p) { ps2[p][cat] = a; a += ps[p][cat]; }
      tot[cat] = a; counts[cat] = a;
    }
    __syncthreads();
    if (tid == 0) {
      int a = 0;
      #pragma unroll
      for (int c = 0; c < 16; ++c) { catbase[c] = a; a += tot[c]; }
    }
    __syncthreads();
    const int base = catbase[cat] + ps2[part][cat];
    #pragma unroll
    for (int i = 0; i < 16; ++i) offs[(part * 16 + i) * 16 + cat] = base + v[i];
  }
}

// ---------------------------------------------------------------------------
// K3 (fused): b<256 scatter (rowidx + posidx) AND (CONV) bf16-convert each of
// the block's 256 rows into Fsrt at its SLOT position — so k_main reads a
// physically sorted, contiguous bf16 array. b>=256: BN params from Gram.
// grid 384 x 256.
// ---------------------------------------------------------------------------
template<bool CONV>
__global__ __launch_bounds__(256) void k_prep(
    const float* __restrict__ F, const int* __restrict__ lab,
    const int* __restrict__ offs,
    const float* __restrict__ G, const float* __restrict__ sv,
    const float* __restrict__ W1, const float* __restrict__ gamma,
    const float* __restrict__ beta,
    int* __restrict__ rowidx, int* __restrict__ posidx,
    unsigned short* __restrict__ Fsrt,
    float* __restrict__ scale, float* __restrict__ shiftv)
{
  __shared__ float Gl[128][133];
  __shared__ float Wl[128][16];
  __shared__ float redq[16][16];
  __shared__ float redm[16][16];
  __shared__ int wc[4][NCAT];
  __shared__ int srows[256];
  const int b = blockIdx.x, tid = threadIdx.x;
  if (b < 256) {
    const int wid = tid >> 6, lane = tid & 63;
    const int n = b * 256 + tid;
    const int c = lab[n];
    const unsigned long long lanebit = 1ull << lane;
    int myrank = 0;
    #pragma unroll
    for (int cc = 0; cc < NCAT; ++cc) {
      unsigned long long m = __ballot(c == cc);
      if (lane == 0) wc[wid][cc] = (int)__popcll(m);
      if (c == cc) myrank = (int)__popcll(m & (lanebit - 1));
    }
    __syncthreads();
    int base = 0;
    #pragma unroll
    for (int w = 0; w < 4; ++w)
      if (w < wid) base += wc[w][c];
    const int slot = offs[b * NCAT + c] + base + myrank;
    rowidx[slot] = n;
    posidx[n] = slot;
    srows[tid] = slot;
    __syncthreads();
    if (CONV) {
      const int t5 = tid & 31;          // 16-B column chunk within a row
      const int rsub = tid >> 5;        // 0..7
      for (int i = 0; i < 32; ++i) {
        const int rl = i * 8 + rsub;    // local row 0..255
        const float4 v = *(const float4*)(F + (size_t)(b * 256 + rl) * 128 + t5 * 4);
        uint2 pk;
        pk.x = pk2(v.x, v.y);
        pk.y = pk2(v.z, v.w);
        *(uint2*)(Fsrt + (size_t)srows[rl] * 128 + t5 * 4) = pk;
      }
    }
  } else {
    const int jb = (b - 256) * 16;
    for (int i = tid; i < 16384; i += 256) Gl[i >> 7][i & 127] = G[i];
    for (int i = tid; i < 2048; i += 256) {
      int k = i >> 4, col = i & 15;
      Wl[k][col] = W1[(size_t)k * 2048 + jb + col];
    }
    __syncthreads();
    const int col = tid & 15, part = tid >> 4;
    float msq = 0.f, mean = 0.f;
    for (int ii = 0; ii < 8; ++ii) {
      const int i = part * 8 + ii;
      const float wi = Wl[i][col];
      float inner = 0.f;
      #pragma unroll 8
      for (int k = 0; k < 128; ++k) inner = fmaf(Gl[i][k], Wl[k][col], inner);
      msq = fmaf(wi, inner, msq);
    }
    #pragma unroll
    for (int kk = 0; kk < 8; ++kk) {
      const int k = part * 8 + kk;
      mean = fmaf(sv[k], Wl[k][col], mean);
    }
    redq[part][col] = msq;
    redm[part][col] = mean;
    __syncthreads();
    if (tid < 16) {
      float q = 0.f, m = 0.f;
      #pragma unroll
      for (int p = 0; p < 16; ++p) { q += redq[p][tid]; m += redm[p][tid]; }
      m *= (1.f / 65536.f);
      q *= (1.f / 65536.f);
      float var = q - m * m;
      float sc = gamma[jb + tid] * rsqrtf(var + 1e-5f);
      scale[jb + tid] = sc;
      shiftv[jb + tid] = beta[jb + tid] - m * sc;
    }
  }
}

// ---------------------------------------------------------------------------
// K4 (fast): category-major MFMA over SORTED bf16 rows. grid = 16 x BCAT;
// 512 thr = 8 waves. W tile in LDS (staged once); A-frags are CONTIGUOUS
// coalesced 16-B global loads from Fsrt (no gather, no f32->bf16 cvt).
// 32-B record per row -> tmp8 at slot position.
// ---------------------------------------------------------------------------
__global__ __launch_bounds__(512) void k_main_f(
    const unsigned short* __restrict__ Fsrt, const unsigned short* __restrict__ Wlb,
    const float* __restrict__ W2p, const float* __restrict__ bias,
    const float* __restrict__ scale, const float* __restrict__ shiftv,
    const int* __restrict__ counts, float* __restrict__ tmp8)
{
  __shared__ __attribute__((aligned(16))) unsigned short Wl[16384];  // 32 KB
  const int tid = threadIdx.x;
  const int cat = (int)blockIdx.x >> 5;
  const int blk = (int)blockIdx.x & (BCAT - 1);
  const int wid = tid >> 6, lane = tid & 63;
  const int lrow = lane & 15, lhi = lane >> 4;

  int off = 0, cnt = 0;
  #pragma unroll
  for (int t = 0; t < NCAT; ++t) {
    int cv = counts[t];
    if (t < cat) off += cv;
    if (t == cat) cnt = cv;
  }
  const int chunk = (cnt + BCAT - 1) / BCAT;
  const int start = off + blk * chunk;
  const int end = min(start + chunk, off + cnt);

  float sc_r[8], sh_r[8];
  #pragma unroll
  for (int ct = 0; ct < 8; ++ct) {
    sc_r[ct] = scale[cat * 128 + ct * 16 + lrow];
    sh_r[ct] = shiftv[cat * 128 + ct * 16 + lrow];
  }
  float bi[6];
  #pragma unroll
  for (int s = 0; s < 6; ++s) bi[s] = bias[s];

  // stage this category's W tile into LDS (coalesced)
  {
    const uint4* src = (const uint4*)(Wlb + (size_t)cat * 16384);
    uint4* dst = (uint4*)Wl;
    for (int i = tid; i < 2048; i += 512) dst[i] = src[i];
  }
  __syncthreads();

  for (int q0 = start + wid * 16; q0 < end; q0 += 128) {
    const unsigned short* fp = Fsrt + (size_t)min(q0 + lrow, end - 1) * 128 + lhi * 8;
    short8v av[4];
    #pragma unroll
    for (int ks = 0; ks < 4; ++ks) av[ks] = *(const short8v*)(fp + ks * 32);

    float4v acc[8];
    #pragma unroll
    for (int ct = 0; ct < 8; ++ct) acc[ct] = (float4v){0.f, 0.f, 0.f, 0.f};

    #pragma unroll
    for (int ks = 0; ks < 4; ++ks) {
      #pragma unroll
      for (int ct = 0; ct < 8; ++ct) {
        const short8v bv = *(const short8v*)(Wl + ((ks * 8 + ct) * 64 + lane) * 8);
        acc[ct] = __builtin_amdgcn_mfma_f32_16x16x32_bf16(av[ks], bv, acc[ct], 0, 0, 0);
      }
    }

    // BN + leaky + W2 partials (lane col c = 16ct+lrow; rows 4*lhi+j)
    float p[4][6];
    #pragma unroll
    for (int j = 0; j < 4; ++j)
      #pragma unroll
      for (int s = 0; s < 6; ++s) p[j][s] = 0.f;
    #pragma unroll
    for (int ct = 0; ct < 8; ++ct) {
      const int c = ct * 16 + lrow;
      const float s_ = sc_r[ct], h_ = sh_r[ct];
      const float4* w2p4 = (const float4*)(W2p + ((size_t)cat * 128 + c) * 8);
      const float4 wa = w2p4[0];
      const float4 wb4 = w2p4[1];
      const float w2v[6] = {wa.x, wa.y, wa.z, wa.w, wb4.x, wb4.y};
      #pragma unroll
      for (int j = 0; j < 4; ++j) {
        float a = acc[ct][j] * s_ + h_;
        a = (a >= 0.f) ? a : 0.2f * a;
        #pragma unroll
        for (int s = 0; s < 6; ++s) p[j][s] = fmaf(a, w2v[s], p[j][s]);
      }
    }
    // reduce-scatter over the 16-lane group: lvl1/2 keep j == lrow&3
    const bool b1 = (lrow & 1) != 0;
    const bool b2 = (lrow & 2) != 0;
    float q[2][6], r[6];
    #pragma unroll
    for (int t = 0; t < 2; ++t)
      #pragma unroll
      for (int s = 0; s < 6; ++s) {
        float snd = b1 ? p[2 * t][s] : p[2 * t + 1][s];
        float kp  = b1 ? p[2 * t + 1][s] : p[2 * t][s];
        q[t][s] = kp + __shfl_xor(snd, 1);
      }
    #pragma unroll
    for (int s = 0; s < 6; ++s) {
      float snd = b2 ? q[0][s] : q[1][s];
      float kp  = b2 ? q[1][s] : q[0][s];
      r[s] = kp + __shfl_xor(snd, 2);
    }
    #pragma unroll
    for (int s = 0; s < 6; ++s) r[s] += __shfl_xor(r[s], 4);
    #pragma unroll
    for (int s = 0; s < 6; ++s) r[s] += __shfl_xor(r[s], 8);

    const int jj = lrow & 3, sb = lrow >> 2;
    const int qrow = min(q0 + 4 * lhi + jj, end - 1);   // slot position
    float pj[6];
    #pragma unroll
    for (int s = 0; s < 6; ++s) pj[s] = r[s] + bi[s];
    float mx = fmaxf(fmaxf(fmaxf(pj[0], pj[1]), fmaxf(pj[2], pj[3])), fmaxf(pj[4], pj[5]));
    float e = __expf(pj[0] - mx) + __expf(pj[1] - mx) + __expf(pj[2] - mx)
            + __expf(pj[3] - mx) + __expf(pj[4] - mx) + __expf(pj[5] - mx);
    float lse = mx + __logf(e);

    float4* trec = (float4*)(tmp8 + (size_t)qrow * 8);
    if (sb == 0) {
      float4 v0; v0.x = pj[0] - lse; v0.y = pj[1] - lse;
      v0.z = pj[2] - lse; v0.w = pj[3] - lse;
      trec[0] = v0;
    } else if (sb == 1) {
      float4 v1; v1.x = pj[4] - lse; v1.y = pj[5] - lse;
      v1.z = 0.f; v1.w = 0.f;
      trec[1] = v1;
    }
  }
}

// ---------------------------------------------------------------------------
// K4 (slow fallback, R14 variant): rowidx-gather from f32 F. Used only if
// ws is too small for Fsrt.
// ---------------------------------------------------------------------------
__global__ __launch_bounds__(512) void k_main(
    const float* __restrict__ F, const unsigned short* __restrict__ Wlb,
    const float* __restrict__ W2p, const float* __restrict__ bias,
    const float* __restrict__ scale, const float* __restrict__ shiftv,
    const int* __restrict__ counts, const int* __restrict__ rowidx,
    float* __restrict__ tmp8)
{
  __shared__ __attribute__((aligned(16))) unsigned short Wl[16384];
  const int tid = threadIdx.x;
  const int cat = (int)blockIdx.x >> 5;
  const int blk = (int)blockIdx.x & (BCAT - 1);
  const int wid = tid >> 6, lane = tid & 63;
  const int lrow = lane & 15, lhi = lane >> 4;

  int off = 0, cnt = 0;
  #pragma unroll
  for (int t = 0; t < NCAT; ++t) {
    int cv = counts[t];
    if (t < cat) off += cv;
    if (t == cat) cnt = cv;
  }
  const int chunk = (cnt + BCAT - 1) / BCAT;
  const int start = off + blk * chunk;
  const int end = min(start + chunk, off + cnt);

  float sc_r[8], sh_r[8];
  #pragma unroll
  for (int ct = 0; ct < 8; ++ct) {
    sc_r[ct] = scale[cat * 128 + ct * 16 + lrow];
    sh_r[ct] = shiftv[cat * 128 + ct * 16 + lrow];
  }
  float bi[6];
  #pragma unroll
  for (int s = 0; s < 6; ++s) bi[s] = bias[s];

  {
    const uint4* src = (const uint4*)(Wlb + (size_t)cat * 16384);
    uint4* dst = (uint4*)Wl;
    for (int i = tid; i < 2048; i += 512) dst[i] = src[i];
  }
  __syncthreads();

  for (int q0 = start + wid * 16; q0 < end; q0 += 128) {
    const int rA = rowidx[min(q0 + lrow, end - 1)];
    const float* fp = F + (size_t)rA * 128 + lhi * 8;
    float4 cA[4], cB[4];
    #pragma unroll
    for (int ks = 0; ks < 4; ++ks) {
      cA[ks] = *(const float4*)(fp + ks * 32);
      cB[ks] = *(const float4*)(fp + ks * 32 + 4);
    }

    float4v acc[8];
    #pragma unroll
    for (int ct = 0; ct < 8; ++ct) acc[ct] = (float4v){0.f, 0.f, 0.f, 0.f};

    #pragma unroll
    for (int ks = 0; ks < 4; ++ks) {
      uint4 av4;
      av4.x = pk2(cA[ks].x, cA[ks].y); av4.y = pk2(cA[ks].z, cA[ks].w);
      av4.z = pk2(cB[ks].x, cB[ks].y); av4.w = pk2(cB[ks].z, cB[ks].w);
      const short8v av = __builtin_bit_cast(short8v, av4);
      #pragma unroll
      for (int ct = 0; ct < 8; ++ct) {
        const short8v bv = *(const short8v*)(Wl + ((ks * 8 + ct) * 64 + lane) * 8);
        acc[ct] = __builtin_amdgcn_mfma_f32_16x16x32_bf16(av, bv, acc[ct], 0, 0, 0);
      }
    }

    float p[4][6];
    #pragma unroll
    for (int j = 0; j < 4; ++j)
      #pragma unroll
      for (int s = 0; s < 6; ++s) p[j][s] = 0.f;
    #pragma unroll
    for (int ct = 0; ct < 8; ++ct) {
      const int c = ct * 16 + lrow;
      const float s_ = sc_r[ct], h_ = sh_r[ct];
      const float4* w2p4 = (const float4*)(W2p + ((size_t)cat * 128 + c) * 8);
      const float4 wa = w2p4[0];
      const float4 wb4 = w2p4[1];
      const float w2v[6] = {wa.x, wa.y, wa.z, wa.w, wb4.x, wb4.y};
      #pragma unroll
      for (int j = 0; j < 4; ++j) {
        float a = acc[ct][j] * s_ + h_;
        a = (a >= 0.f) ? a : 0.2f * a;
        #pragma unroll
        for (int s = 0; s < 6; ++s) p[j][s] = fmaf(a, w2v[s], p[j][s]);
      }
    }
    const bool b1 = (lrow & 1) != 0;
    const bool b2 = (lrow & 2) != 0;
    float q[2][6], r[6];
    #pragma unroll
    for (int t = 0; t < 2; ++t)
      #pragma unroll
      for (int s = 0; s < 6; ++s) {
        float snd = b1 ? p[2 * t][s] : p[2 * t + 1][s];
        float kp  = b1 ? p[2 * t + 1][s] : p[2 * t][s];
        q[t][s] = kp + __shfl_xor(snd, 1);
      }
    #pragma unroll
    for (int s = 0; s < 6; ++s) {
      float snd = b2 ? q[0][s] : q[1][s];
      float kp  = b2 ? q[1][s] : q[0][s];
      r[s] = kp + __shfl_xor(snd, 2);
    }
    #pragma unroll
    for (int s = 0; s < 6; ++s) r[s] += __shfl_xor(r[s], 4);
    #pragma unroll
    for (int s = 0; s < 6; ++s) r[s] += __shfl_xor(r[s], 8);

    const int jj = lrow & 3, sb = lrow >> 2;
    const int qrow = min(q0 + 4 * lhi + jj, end - 1);
    float pj[6];
    #pragma unroll
    for (int s = 0; s < 6; ++s) pj[s] = r[s] + bi[s];
    float mx = fmaxf(fmaxf(fmaxf(pj[0], pj[1]), fmaxf(pj[2], pj[3])), fmaxf(pj[4], pj[5]));
    float e = __expf(pj[0] - mx) + __expf(pj[1] - mx) + __expf(pj[2] - mx)
            + __expf(pj[3] - mx) + __expf(pj[4] - mx) + __expf(pj[5] - mx);
    float lse = mx + __logf(e);

    float4* trec = (float4*)(tmp8 + (size_t)qrow * 8);
    if (sb == 0) {
      float4 v0; v0.x = pj[0] - lse; v0.y = pj[1] - lse;
      v0.z = pj[2] - lse; v0.w = pj[3] - lse;
      trec[0] = v0;
    } else if (sb == 1) {
      float4 v1; v1.x = pj[4] - lse; v1.y = pj[5] - lse;
      v1.z = 0.f; v1.w = 0.f;
      trec[1] = v1;
    }
  }
}

// ---------------------------------------------------------------------------
// K5: permute records -> dense output in OUTPUT order (fully coalesced
// full-line stores, no RMW). grid 6912 x 256 (one float2/thread).
// ---------------------------------------------------------------------------
__global__ __launch_bounds__(256) void k_out(
    const float* __restrict__ tmp8, const int* __restrict__ lab,
    const int* __restrict__ posidx, float* __restrict__ out)
{
  const int i2 = blockIdx.x * 256 + threadIdx.x;  // 0 .. 65536*27
  const int n = i2 / 27;
  const int j2 = i2 - n * 27;
  const int c = lab[n];
  const int shc = c_shift[c], lnc = c_len[c];
  const float* rec = tmp8 + (size_t)posidx[n] * 8;
  const int s0 = 2 * j2 - shc;
  float2 v; v.x = 0.f; v.y = 0.f;
  if (s0 >= 0 && s0 < lnc)         v.x = rec[s0];
  if (s0 + 1 >= 0 && s0 + 1 < lnc) v.y = rec[s0 + 1];
  ((float2*)out)[i2] = v;
}

// ---------------------------------------------------------------------------
// Host launcher — 5 launches (fast path).
// ---------------------------------------------------------------------------
extern "C" void kernel_launch(void* const* d_in, const int* in_sizes, int n_in,
                              void* d_out, int out_size, void* d_ws, size_t ws_size,
                              hipStream_t stream) {
  const float* F     = (const float*)d_in[0];
  const float* W1    = (const float*)d_in[1];
  const float* gamma = (const float*)d_in[2];
  const float* beta  = (const float*)d_in[3];
  const float* W2    = (const float*)d_in[4];
  const float* bias  = (const float*)d_in[5];
  const int*   lab   = (const int*)d_in[6];
  float* out = (float*)d_out;

  char* ws = (char*)d_ws;
  float* sv      = (float*)(ws + 0);
  int*   counts  = (int*)(ws + 512);
  int*   blkcnt  = (int*)(ws + 576);
  int*   offs    = (int*)(ws + 16960);
  float* scale   = (float*)(ws + 33344);
  float* shiftv  = (float*)(ws + 41536);
  float* G       = (float*)(ws + 49728);
  int*   rowidx  = (int*)(ws + 115264);
  int*   posidx  = (int*)(ws + 377408);
  unsigned short* Wlb = (unsigned short*)(ws + 639552);
  float* W2p     = (float*)(ws + 1163840);
  float* tmp8    = (float*)(ws + 1229376);
  unsigned* Gp16 = (unsigned*)(ws + 3326528);
  float* svpart  = (float*)(ws + 11715136);
  unsigned short* Fsrt = (unsigned short*)(ws + 3326528);  // overlays Gp16+svpart

  const size_t need = 3326528 + (size_t)65536 * 128 * 2;  // ~20.1 MB
  const int fast = (ws_size >= need) ? 1 : 0;
  if (fast) {
    hipLaunchKernelGGL(k_stats_m<true>, dim3(272), dim3(1024), 0, stream,
                       F, W1, W2, lab, G, Gp16, sv, svpart, blkcnt, Wlb, W2p);
    hipLaunchKernelGGL(k_mid, dim3(34), dim3(256), 0, stream,
                       Gp16, svpart, blkcnt, G, sv, offs, counts, 1);
    hipLaunchKernelGGL(k_prep<true>, dim3(384), dim3(256), 0, stream,
                       F, lab, offs, G, sv, W1, gamma, beta,
                       rowidx, posidx, Fsrt, scale, shiftv);
    hipLaunchKernelGGL(k_main_f, dim3(NCAT * BCAT), dim3(512), 0, stream,
                       Fsrt, Wlb, W2p, bias, scale, shiftv, counts, tmp8);
  } else {
    hipMemsetAsync(d_ws, 0, 115264, stream);  // sv + G (+counts/blkcnt harmless)
    hipLaunchKernelGGL(k_stats_m<false>, dim3(272), dim3(1024), 0, stream,
                       F, W1, W2, lab, G, Gp16, sv, svpart, blkcnt, Wlb, W2p);
    hipLaunchKernelGGL(k_mid, dim3(34), dim3(256), 0, stream,
                       Gp16, svpart, blkcnt, G, sv, offs, counts, 0);
    hipLaunchKernelGGL(k_prep<false>, dim3(384), dim3(256), 0, stream,
                       F, lab, offs, G, sv, W1, gamma, beta,
                       rowidx, posidx, Fsrt, scale, shiftv);
    hipLaunchKernelGGL(k_main, dim3(NCAT * BCAT), dim3(512), 0, stream,
                       F, Wlb, W2p, bias, scale, shiftv, counts, rowidx, tmp8);
  }
  hipLaunchKernelGGL(k_out, dim3(6912), dim3(256), 0, stream,
                     tmp8, lab, posidx, out);
}

// Round 16
// 77.287 us; speedup vs baseline: 1.2873x; 1.1605x over previous
//
#include <hip/hip_runtime.h>
#include <hip/hip_bf16.h>

#define NCAT 16
#define BCAT 32   // blocks per category in k_main

typedef __attribute__((ext_vector_type(8))) short short8v;
typedef __attribute__((ext_vector_type(4))) float float4v;
typedef __attribute__((ext_vector_type(16))) float f32x16;

__constant__ int c_shift[NCAT] = {0,4,6,8,12,16,19,22,24,28,34,36,42,45,48,51};
__constant__ int c_len[NCAT]   = {4,2,2,4,4,3,3,2,4,6,2,6,3,3,3,3};

// ws layout (bytes):
//   sv      @ 0        (128 f32)   -> 512
//   counts  @ 512      (16 i32)    -> 576
//   blkcnt  @ 576      (256*16)    -> 16960
//   offs    @ 16960    (256*16)    -> 33344
//   scale   @ 33344    (2048 f32)  -> 41536
//   shiftv  @ 41536    (2048 f32)  -> 49728
//   G       @ 49728    (16384 f32) -> 115264
//   rowidx  @ 115264   (65536 i32) -> 377408
//   posidx  @ 377408   (65536 i32) -> 639552
//   Wlb     @ 639552   (512 KB)    -> 1163840
//   W2p     @ 1163840  (64 KB)     -> 1229376
//   tmp8    @ 1229376  (2 MB)      -> 3326528
//   Gp16    @ 3326528  (8 MB)      -> 11715136  [dead after k_mid]
//   svpart  @ 11715136 (128 KB)    -> 11846208  need ~11.85 MB

static inline __device__ unsigned pk2(float lo, float hi) {
  float2 f2; f2.x = lo; f2.y = hi;
  __hip_bfloat162 h = __float22bfloat162_rn(f2);
  unsigned u; __builtin_memcpy(&u, &h, 4);
  return u;
}
static inline __device__ float bf2f(unsigned short v) {
  unsigned u = (unsigned)v << 16;
  float f; __builtin_memcpy(&f, &u, 4);
  return f;
}

// ---------------------------------------------------------------------------
// K1: blocks 0..255 = MFMA Gram (256 rows, 16 waves, 32x32 tiles, bf16
// partials) + label histogram -> blkcnt. Blocks 256..271 = W1 pre-swizzle
// into MFMA B-frag layout + padded W2p table (one cat per block).
// ---------------------------------------------------------------------------
template<bool PART>
__global__ __launch_bounds__(1024) void k_stats_m(
    const float* __restrict__ F, const float* __restrict__ W1,
    const float* __restrict__ W2, const int* __restrict__ lab,
    float* __restrict__ Gdst, unsigned* __restrict__ Gp16,
    float* __restrict__ sv, float* __restrict__ svpart,
    int* __restrict__ blkcnt, unsigned short* __restrict__ Wlb,
    float* __restrict__ W2p)
{
  const int tid = threadIdx.x;
  if (blockIdx.x >= 256) {
    const int cat = (int)blockIdx.x - 256;
    for (int e = tid; e < 2048; e += 1024) {
      const int fid = e >> 6, l = e & 63;
      const int ks = fid >> 3, ct = fid & 7;
      const int kb = 32 * ks + 8 * (l >> 4);
      const int c = cat * 128 + 16 * ct + (l & 15);
      uint4 pk;
      pk.x = pk2(W1[(size_t)(kb + 0) * 2048 + c], W1[(size_t)(kb + 1) * 2048 + c]);
      pk.y = pk2(W1[(size_t)(kb + 2) * 2048 + c], W1[(size_t)(kb + 3) * 2048 + c]);
      pk.z = pk2(W1[(size_t)(kb + 4) * 2048 + c], W1[(size_t)(kb + 5) * 2048 + c]);
      pk.w = pk2(W1[(size_t)(kb + 6) * 2048 + c], W1[(size_t)(kb + 7) * 2048 + c]);
      *(uint4*)(Wlb + ((size_t)(cat * 32 + fid) * 64 + l) * 8) = pk;
    }
    if (tid < 1024) {
      const int c = tid >> 3, s = tid & 7;
      W2p[cat * 1024 + tid] = (s < 6) ? W2[cat * 768 + c * 6 + s] : 0.f;
    }
    return;
  }

  __shared__ int hl[NCAT];
  if (tid < NCAT) hl[tid] = 0;
  __syncthreads();
  const int rowbase = blockIdx.x * 256;
  if (tid < 256) atomicAdd(&hl[lab[rowbase + tid]], 1);

  const int wid = tid >> 6, lane = tid & 63;
  const int wi = wid >> 2, wj = wid & 3;
  const int i0 = wi * 32, j0 = wj * 32;
  const int lr = lane & 31, lh = lane >> 5;

  f32x16 acc;
  #pragma unroll
  for (int e = 0; e < 16; ++e) acc[e] = 0.f;
  float svacc = 0.f;

  for (int ch = 0; ch < 8; ++ch) {
    #pragma unroll
    for (int h = 0; h < 2; ++h) {
      const int rbase = rowbase + ch * 32 + 16 * h + 8 * lh;
      float fa[8], fb[8];
      #pragma unroll
      for (int j = 0; j < 8; ++j) {
        const float* rp = F + (size_t)(rbase + j) * 128;
        fa[j] = rp[i0 + lr];
        fb[j] = rp[j0 + lr];
      }
      if (wj == 0) {
        #pragma unroll
        for (int j = 0; j < 8; ++j) svacc += fa[j];
      }
      uint4 av4, bv4;
      av4.x = pk2(fa[0], fa[1]); av4.y = pk2(fa[2], fa[3]);
      av4.z = pk2(fa[4], fa[5]); av4.w = pk2(fa[6], fa[7]);
      bv4.x = pk2(fb[0], fb[1]); bv4.y = pk2(fb[2], fb[3]);
      bv4.z = pk2(fb[4], fb[5]); bv4.w = pk2(fb[6], fb[7]);
      acc = __builtin_amdgcn_mfma_f32_32x32x16_bf16(
          __builtin_bit_cast(short8v, av4), __builtin_bit_cast(short8v, bv4),
          acc, 0, 0, 0);
    }
  }

  if (wj == 0) {
    svacc += __shfl_xor(svacc, 32);
    if (lane < 32) {
      if (PART) svpart[blockIdx.x * 128 + i0 + lr] = svacc;
      else      atomicAdd(&sv[i0 + lr], svacc);
    }
  }
  __syncthreads();
  if (tid < NCAT) blkcnt[blockIdx.x * NCAT + tid] = hl[tid];

  if (PART) {
    unsigned* gp = Gp16 + (size_t)blockIdx.x * 8192;
    #pragma unroll
    for (int t = 0; t < 8; ++t) {
      const int rowe = ((2 * t) & 3) + 8 * (t >> 1) + 4 * lh;   // even row of pair
      gp[((i0 + rowe) >> 1) * 128 + j0 + lr] = pk2(acc[2 * t], acc[2 * t + 1]);
    }
  } else {
    #pragma unroll
    for (int reg = 0; reg < 16; ++reg) {
      const int row = (reg & 3) + 8 * (reg >> 2) + 4 * lh;
      atomicAdd(&Gdst[(i0 + row) * 128 + j0 + lr], acc[reg]);
    }
  }
}

// ---------------------------------------------------------------------------
// K2 (fused): b<64 G-reduce (bf16 pairs, 2 threads/elem half-split + shfl);
// b==64 sv-reduce; b==65 prefix sums over blkcnt -> offs + counts.
// grid 66 x 256.
// ---------------------------------------------------------------------------
__global__ __launch_bounds__(256) void k_mid(
    const unsigned* __restrict__ Gp16, const float* __restrict__ svpart,
    const int* __restrict__ blkcnt, float* __restrict__ G,
    float* __restrict__ sv, int* __restrict__ offs,
    int* __restrict__ counts, int doRed)
{
  __shared__ int ps[16][16], ps2[16][16], tot[16], catbase[16];
  const int b = blockIdx.x, tid = threadIdx.x;
  if (b < 64) {
    if (!doRed) return;
    const int e = b * 128 + (tid >> 1);    // pair index 0..8191
    const int half = tid & 1;
    float lo = 0.f, hi = 0.f;
    #pragma unroll 4
    for (int p = half * 128; p < half * 128 + 128; ++p) {
      const unsigned u = Gp16[(size_t)p * 8192 + e];
      lo += bf2f((unsigned short)(u & 0xffffu));
      hi += bf2f((unsigned short)(u >> 16));
    }
    lo += __shfl_xor(lo, 1);
    hi += __shfl_xor(hi, 1);
    if (half == 0) {
      const int pr = e >> 7, col = e & 127;
      G[(2 * pr) * 128 + col]     = lo;
      G[(2 * pr + 1) * 128 + col] = hi;
    }
  } else if (b == 64) {
    if (!doRed) return;
    if (tid < 128) {
      float s = 0.f;
      #pragma unroll 8
      for (int p = 0; p < 256; ++p) s += svpart[p * 128 + tid];
      sv[tid] = s;
    }
  } else {
    const int part = tid >> 4, cat = tid & 15;
    int v[16]; int s = 0;
    #pragma unroll
    for (int i = 0; i < 16; ++i) { v[i] = s; s += blkcnt[(part * 16 + i) * 16 + cat]; }
    ps[part][cat] = s;
    __syncthreads();
    if (part == 0) {
      int a = 0;
      #pragma unroll
      for (int p = 0; p < 16; ++p) { ps2[p][cat] = a; a += ps[p][cat]; }
      tot[cat] = a; counts[cat] = a;
    }
    __syncthreads();
    if (tid == 0) {
      int a = 0;
      #pragma unroll
      for (int c = 0; c < 16; ++c) { catbase[c] = a; a += tot[c]; }
    }
    __syncthreads();
    const int base = catbase[cat] + ps2[part][cat];
    #pragma unroll
    for (int i = 0; i < 16; ++i) offs[(part * 16 + i) * 16 + cat] = base + v[i];
  }
}

// ---------------------------------------------------------------------------
// K3 (fused): b<256 scatter (rowidx + posidx, atomic-free, deterministic);
// b>=256 BN params from Gram. grid 384 x 256.
// ---------------------------------------------------------------------------
__global__ __launch_bounds__(256) void k_prep(
    const int* __restrict__ lab, const int* __restrict__ offs,
    const float* __restrict__ G, const float* __restrict__ sv,
    const float* __restrict__ W1, const float* __restrict__ gamma,
    const float* __restrict__ beta,
    int* __restrict__ rowidx, int* __restrict__ posidx,
    float* __restrict__ scale, float* __restrict__ shiftv)
{
  __shared__ float Gl[128][133];
  __shared__ float Wl[128][16];
  __shared__ float redq[16][16];
  __shared__ float redm[16][16];
  __shared__ int wc[4][NCAT];
  const int b = blockIdx.x, tid = threadIdx.x;
  if (b < 256) {
    const int wid = tid >> 6, lane = tid & 63;
    const int n = b * 256 + tid;
    const int c = lab[n];
    const unsigned long long lanebit = 1ull << lane;
    int myrank = 0;
    #pragma unroll
    for (int cc = 0; cc < NCAT; ++cc) {
      unsigned long long m = __ballot(c == cc);
      if (lane == 0) wc[wid][cc] = (int)__popcll(m);
      if (c == cc) myrank = (int)__popcll(m & (lanebit - 1));
    }
    __syncthreads();
    int base = 0;
    #pragma unroll
    for (int w = 0; w < 4; ++w)
      if (w < wid) base += wc[w][c];
    const int slot = offs[b * NCAT + c] + base + myrank;
    rowidx[slot] = n;
    posidx[n] = slot;
  } else {
    const int jb = (b - 256) * 16;
    for (int i = tid; i < 16384; i += 256) Gl[i >> 7][i & 127] = G[i];
    for (int i = tid; i < 2048; i += 256) {
      int k = i >> 4, col = i & 15;
      Wl[k][col] = W1[(size_t)k * 2048 + jb + col];
    }
    __syncthreads();
    const int col = tid & 15, part = tid >> 4;
    float msq = 0.f, mean = 0.f;
    for (int ii = 0; ii < 8; ++ii) {
      const int i = part * 8 + ii;
      const float wi = Wl[i][col];
      float inner = 0.f;
      #pragma unroll 8
      for (int k = 0; k < 128; ++k) inner = fmaf(Gl[i][k], Wl[k][col], inner);
      msq = fmaf(wi, inner, msq);
    }
    #pragma unroll
    for (int kk = 0; kk < 8; ++kk) {
      const int k = part * 8 + kk;
      mean = fmaf(sv[k], Wl[k][col], mean);
    }
    redq[part][col] = msq;
    redm[part][col] = mean;
    __syncthreads();
    if (tid < 16) {
      float q = 0.f, m = 0.f;
      #pragma unroll
      for (int p = 0; p < 16; ++p) { q += redq[p][tid]; m += redm[p][tid]; }
      m *= (1.f / 65536.f);
      q *= (1.f / 65536.f);
      float var = q - m * m;
      float sc = gamma[jb + tid] * rsqrtf(var + 1e-5f);
      scale[jb + tid] = sc;
      shiftv[jb + tid] = beta[jb + tid] - m * sc;
    }
  }
}

// ---------------------------------------------------------------------------
// K4: category-major MFMA main with IN-KERNEL row-cooperative gather.
// grid = 16 cat x BCAT(32); 512 thr = 8 waves. W tile (32 KB) staged once;
// per 128-row window: gather rows via rowidx (32 lanes x 16B = contiguous
// 512-B segments, line-sequential), convert bf16, store to LDS with R12's
// verified XOR swizzle; barrier; 1 group/wave via swizzled ds_read_b128 +
// MFMA + verified epilogue. 32-B record/row -> tmp8 at slot position.
// No Fsrt, no per-group global latency. LDS 64 KB -> 2 blocks/CU.
// ---------------------------------------------------------------------------
__global__ __launch_bounds__(512) void k_main_g(
    const float* __restrict__ F, const unsigned short* __restrict__ Wlb,
    const float* __restrict__ W2p, const float* __restrict__ bias,
    const float* __restrict__ scale, const float* __restrict__ shiftv,
    const int* __restrict__ counts, const int* __restrict__ rowidx,
    float* __restrict__ tmp8)
{
  __shared__ __attribute__((aligned(16))) unsigned short Wl[16384];    // 32 KB
  __shared__ __attribute__((aligned(16))) unsigned short Flds[16384];  // 32 KB: 128 rows x 256 B
  const int tid = threadIdx.x;
  const int cat = (int)blockIdx.x >> 5;
  const int blk = (int)blockIdx.x & (BCAT - 1);
  const int wid = tid >> 6, lane = tid & 63;
  const int lrow = lane & 15, lhi = lane >> 4;

  int off = 0, cnt = 0;
  #pragma unroll
  for (int t = 0; t < NCAT; ++t) {
    int cv = counts[t];
    if (t < cat) off += cv;
    if (t == cat) cnt = cv;
  }
  const int chunk = (cnt + BCAT - 1) / BCAT;
  const int start = off + blk * chunk;
  const int end = min(start + chunk, off + cnt);

  // stage this category's W tile into LDS (coalesced)
  {
    const uint4* src = (const uint4*)(Wlb + (size_t)cat * 16384);
    uint4* dst = (uint4*)Wl;
    for (int i = tid; i < 2048; i += 512) dst[i] = src[i];
  }
  if (start >= end) return;   // block-uniform: safe (no barrier crossed yet)

  float sc_r[8], sh_r[8];
  #pragma unroll
  for (int ct = 0; ct < 8; ++ct) {
    sc_r[ct] = scale[cat * 128 + ct * 16 + lrow];
    sh_r[ct] = shiftv[cat * 128 + ct * 16 + lrow];
  }
  float bi[6];
  #pragma unroll
  for (int s = 0; s < 6; ++s) bi[s] = bias[s];

  const int rsub = tid >> 5, t5 = tid & 31;   // 16 rows in flight, 32 lanes/row

  for (int w0 = start; w0 < end; w0 += 128) {
    const int nrows = min(128, end - w0);
    __syncthreads();   // Wl ready (1st iter) / previous window's readers done
    // gather + convert 128 rows into swizzled LDS
    #pragma unroll
    for (int i = 0; i < 8; ++i) {
      const int rl = i * 16 + rsub;                      // 0..127
      const int rsrc = rowidx[w0 + min(rl, nrows - 1)];  // broadcast per half-wave
      const float4 v = *(const float4*)(F + (size_t)rsrc * 128 + t5 * 4);
      uint2 pk;
      pk.x = pk2(v.x, v.y);
      pk.y = pk2(v.z, v.w);
      *(uint2*)((char*)Flds + rl * 256 + ((t5 * 8) ^ ((rl & 7) << 4))) = pk;
    }
    __syncthreads();   // Flds ready

    const int q0 = w0 + wid * 16;
    if (q0 < end) {
      const int lq = min(q0 + lrow, w0 + nrows - 1) - w0;   // local A row
      short8v av[4];
      #pragma unroll
      for (int ks = 0; ks < 4; ++ks) {
        const int co = (ks * 64 + lhi * 16) ^ ((lq & 7) << 4);
        av[ks] = *(const short8v*)((const char*)Flds + lq * 256 + co);
      }

      float4v acc[8];
      #pragma unroll
      for (int ct = 0; ct < 8; ++ct) acc[ct] = (float4v){0.f, 0.f, 0.f, 0.f};

      #pragma unroll
      for (int ks = 0; ks < 4; ++ks) {
        #pragma unroll
        for (int ct = 0; ct < 8; ++ct) {
          const short8v bv = *(const short8v*)(Wl + ((ks * 8 + ct) * 64 + lane) * 8);
          acc[ct] = __builtin_amdgcn_mfma_f32_16x16x32_bf16(av[ks], bv, acc[ct], 0, 0, 0);
        }
      }

      // BN + leaky + W2 partials (lane col c = 16ct+lrow; rows 4*lhi+j)
      float p[4][6];
      #pragma unroll
      for (int j = 0; j < 4; ++j)
        #pragma unroll
        for (int s = 0; s < 6; ++s) p[j][s] = 0.f;
      #pragma unroll
      for (int ct = 0; ct < 8; ++ct) {
        const int c = ct * 16 + lrow;
        const float s_ = sc_r[ct], h_ = sh_r[ct];
        const float4* w2p4 = (const float4*)(W2p + ((size_t)cat * 128 + c) * 8);
        const float4 wa = w2p4[0];
        const float4 wb4 = w2p4[1];
        const float w2v[6] = {wa.x, wa.y, wa.z, wa.w, wb4.x, wb4.y};
        #pragma unroll
        for (int j = 0; j < 4; ++j) {
          float a = acc[ct][j] * s_ + h_;
          a = (a >= 0.f) ? a : 0.2f * a;
          #pragma unroll
          for (int s = 0; s < 6; ++s) p[j][s] = fmaf(a, w2v[s], p[j][s]);
        }
      }
      // reduce-scatter over the 16-lane group: lvl1/2 keep j == lrow&3
      const bool b1 = (lrow & 1) != 0;
      const bool b2 = (lrow & 2) != 0;
      float q[2][6], r[6];
      #pragma unroll
      for (int t = 0; t < 2; ++t)
        #pragma unroll
        for (int s = 0; s < 6; ++s) {
          float snd = b1 ? p[2 * t][s] : p[2 * t + 1][s];
          float kp  = b1 ? p[2 * t + 1][s] : p[2 * t][s];
          q[t][s] = kp + __shfl_xor(snd, 1);
        }
      #pragma unroll
      for (int s = 0; s < 6; ++s) {
        float snd = b2 ? q[0][s] : q[1][s];
        float kp  = b2 ? q[1][s] : q[0][s];
        r[s] = kp + __shfl_xor(snd, 2);
      }
      #pragma unroll
      for (int s = 0; s < 6; ++s) r[s] += __shfl_xor(r[s], 4);
      #pragma unroll
      for (int s = 0; s < 6; ++s) r[s] += __shfl_xor(r[s], 8);

      const int jj = lrow & 3, sb = lrow >> 2;
      const int qrow = min(q0 + 4 * lhi + jj, end - 1);   // slot position
      float pj[6];
      #pragma unroll
      for (int s = 0; s < 6; ++s) pj[s] = r[s] + bi[s];
      float mx = fmaxf(fmaxf(fmaxf(pj[0], pj[1]), fmaxf(pj[2], pj[3])), fmaxf(pj[4], pj[5]));
      float e = __expf(pj[0] - mx) + __expf(pj[1] - mx) + __expf(pj[2] - mx)
              + __expf(pj[3] - mx) + __expf(pj[4] - mx) + __expf(pj[5] - mx);
      float lse = mx + __logf(e);

      float4* trec = (float4*)(tmp8 + (size_t)qrow * 8);
      if (sb == 0) {
        float4 v0; v0.x = pj[0] - lse; v0.y = pj[1] - lse;
        v0.z = pj[2] - lse; v0.w = pj[3] - lse;
        trec[0] = v0;
      } else if (sb == 1) {
        float4 v1; v1.x = pj[4] - lse; v1.y = pj[5] - lse;
        v1.z = 0.f; v1.w = 0.f;
        trec[1] = v1;
      }
    }
  }
}

// ---------------------------------------------------------------------------
// K5: permute records -> dense output in OUTPUT order (fully coalesced
// full-line stores, no RMW). grid 6912 x 256 (one float2/thread).
// ---------------------------------------------------------------------------
__global__ __launch_bounds__(256) void k_out(
    const float* __restrict__ tmp8, const int* __restrict__ lab,
    const int* __restrict__ posidx, float* __restrict__ out)
{
  const int i2 = blockIdx.x * 256 + threadIdx.x;  // 0 .. 65536*27
  const int n = i2 / 27;
  const int j2 = i2 - n * 27;
  const int c = lab[n];
  const int shc = c_shift[c], lnc = c_len[c];
  const float* rec = tmp8 + (size_t)posidx[n] * 8;
  const int s0 = 2 * j2 - shc;
  float2 v; v.x = 0.f; v.y = 0.f;
  if (s0 >= 0 && s0 < lnc)         v.x = rec[s0];
  if (s0 + 1 >= 0 && s0 + 1 < lnc) v.y = rec[s0 + 1];
  ((float2*)out)[i2] = v;
}

// ---------------------------------------------------------------------------
// Host launcher — 5 launches (both paths share everything but k_stats mode).
// ---------------------------------------------------------------------------
extern "C" void kernel_launch(void* const* d_in, const int* in_sizes, int n_in,
                              void* d_out, int out_size, void* d_ws, size_t ws_size,
                              hipStream_t stream) {
  const float* F     = (const float*)d_in[0];
  const float* W1    = (const float*)d_in[1];
  const float* gamma = (const float*)d_in[2];
  const float* beta  = (const float*)d_in[3];
  const float* W2    = (const float*)d_in[4];
  const float* bias  = (const float*)d_in[5];
  const int*   lab   = (const int*)d_in[6];
  float* out = (float*)d_out;

  char* ws = (char*)d_ws;
  float* sv      = (float*)(ws + 0);
  int*   counts  = (int*)(ws + 512);
  int*   blkcnt  = (int*)(ws + 576);
  int*   offs    = (int*)(ws + 16960);
  float* scale   = (float*)(ws + 33344);
  float* shiftv  = (float*)(ws + 41536);
  float* G       = (float*)(ws + 49728);
  int*   rowidx  = (int*)(ws + 115264);
  int*   posidx  = (int*)(ws + 377408);
  unsigned short* Wlb = (unsigned short*)(ws + 639552);
  float* W2p     = (float*)(ws + 1163840);
  float* tmp8    = (float*)(ws + 1229376);
  unsigned* Gp16 = (unsigned*)(ws + 3326528);
  float* svpart  = (float*)(ws + 11715136);

  const size_t need = 11846208;  // ~11.85 MB
  const int fast = (ws_size >= need) ? 1 : 0;
  if (fast) {
    hipLaunchKernelGGL(k_stats_m<true>, dim3(272), dim3(1024), 0, stream,
                       F, W1, W2, lab, G, Gp16, sv, svpart, blkcnt, Wlb, W2p);
  } else {
    hipMemsetAsync(d_ws, 0, 115264, stream);  // sv + G (+counts/blkcnt harmless)
    hipLaunchKernelGGL(k_stats_m<false>, dim3(272), dim3(1024), 0, stream,
                       F, W1, W2, lab, G, Gp16, sv, svpart, blkcnt, Wlb, W2p);
  }
  hipLaunchKernelGGL(k_mid, dim3(66), dim3(256), 0, stream,
                     Gp16, svpart, blkcnt, G, sv, offs, counts, fast);
  hipLaunchKernelGGL(k_prep, dim3(384), dim3(256), 0, stream,
                     lab, offs, G, sv, W1, gamma, beta, rowidx, posidx, scale, shiftv);
  hipLaunchKernelGGL(k_main_g, dim3(NCAT * BCAT), dim3(512), 0, stream,
                     F, Wlb, W2p, bias, scale, shiftv, counts, rowidx, tmp8);
  hipLaunchKernelGGL(k_out, dim3(6912), dim3(256), 0, stream,
                     tmp8, lab, posidx, out);
}

// Round 17
// 73.709 us; speedup vs baseline: 1.3498x; 1.0485x over previous
//
#include <hip/hip_runtime.h>
#include <hip/hip_bf16.h>

#define NCAT 16
#define BCAT 32   // blocks per category in k_main

typedef __attribute__((ext_vector_type(8))) short short8v;
typedef __attribute__((ext_vector_type(4))) float float4v;
typedef __attribute__((ext_vector_type(16))) float f32x16;

__constant__ int c_shift[NCAT] = {0,4,6,8,12,16,19,22,24,28,34,36,42,45,48,51};
__constant__ int c_len[NCAT]   = {4,2,2,4,4,3,3,2,4,6,2,6,3,3,3,3};

// ws layout (bytes):
//   sv      @ 0        (128 f32)   -> 512
//   counts  @ 512      (16 i32)    -> 576
//   blkcnt  @ 576      (256*16)    -> 16960
//   offs    @ 16960    (256*16)    -> 33344
//   scale   @ 33344    (2048 f32)  -> 41536
//   shiftv  @ 41536    (2048 f32)  -> 49728
//   G       @ 49728    (16384 f32) -> 115264
//   rowidx  @ 115264   (65536 i32) -> 377408
//   posidx  @ 377408   (65536 i32) -> 639552
//   Wlb     @ 639552   (512 KB)    -> 1163840
//   W2p     @ 1163840  (64 KB)     -> 1229376
//   tmp8    @ 1229376  (2 MB)      -> 3326528
//   Gp16    @ 3326528  (8 MB)      -> 11715136  [dead after k_mid]
//   svpart  @ 11715136 (128 KB)    -> 11846208  need ~11.85 MB

static inline __device__ unsigned pk2(float lo, float hi) {
  float2 f2; f2.x = lo; f2.y = hi;
  __hip_bfloat162 h = __float22bfloat162_rn(f2);
  unsigned u; __builtin_memcpy(&u, &h, 4);
  return u;
}
static inline __device__ float bf2f(unsigned short v) {
  unsigned u = (unsigned)v << 16;
  float f; __builtin_memcpy(&f, &u, 4);
  return f;
}

// ---------------------------------------------------------------------------
// K1: blocks 0..255 = MFMA Gram (256 rows, 16 waves, 32x32 tiles, bf16
// partials) + label histogram -> blkcnt. Blocks 256..271 = W1 pre-swizzle
// into MFMA B-frag layout + padded W2p table (one cat per block).
// ---------------------------------------------------------------------------
template<bool PART>
__global__ __launch_bounds__(1024) void k_stats_m(
    const float* __restrict__ F, const float* __restrict__ W1,
    const float* __restrict__ W2, const int* __restrict__ lab,
    float* __restrict__ Gdst, unsigned* __restrict__ Gp16,
    float* __restrict__ sv, float* __restrict__ svpart,
    int* __restrict__ blkcnt, unsigned short* __restrict__ Wlb,
    float* __restrict__ W2p)
{
  const int tid = threadIdx.x;
  if (blockIdx.x >= 256) {
    const int cat = (int)blockIdx.x - 256;
    for (int e = tid; e < 2048; e += 1024) {
      const int fid = e >> 6, l = e & 63;
      const int ks = fid >> 3, ct = fid & 7;
      const int kb = 32 * ks + 8 * (l >> 4);
      const int c = cat * 128 + 16 * ct + (l & 15);
      uint4 pk;
      pk.x = pk2(W1[(size_t)(kb + 0) * 2048 + c], W1[(size_t)(kb + 1) * 2048 + c]);
      pk.y = pk2(W1[(size_t)(kb + 2) * 2048 + c], W1[(size_t)(kb + 3) * 2048 + c]);
      pk.z = pk2(W1[(size_t)(kb + 4) * 2048 + c], W1[(size_t)(kb + 5) * 2048 + c]);
      pk.w = pk2(W1[(size_t)(kb + 6) * 2048 + c], W1[(size_t)(kb + 7) * 2048 + c]);
      *(uint4*)(Wlb + ((size_t)(cat * 32 + fid) * 64 + l) * 8) = pk;
    }
    if (tid < 1024) {
      const int c = tid >> 3, s = tid & 7;
      W2p[cat * 1024 + tid] = (s < 6) ? W2[cat * 768 + c * 6 + s] : 0.f;
    }
    return;
  }

  __shared__ int hl[NCAT];
  if (tid < NCAT) hl[tid] = 0;
  __syncthreads();
  const int rowbase = blockIdx.x * 256;
  if (tid < 256) atomicAdd(&hl[lab[rowbase + tid]], 1);

  const int wid = tid >> 6, lane = tid & 63;
  const int wi = wid >> 2, wj = wid & 3;
  const int i0 = wi * 32, j0 = wj * 32;
  const int lr = lane & 31, lh = lane >> 5;

  f32x16 acc;
  #pragma unroll
  for (int e = 0; e < 16; ++e) acc[e] = 0.f;
  float svacc = 0.f;

  for (int ch = 0; ch < 8; ++ch) {
    #pragma unroll
    for (int h = 0; h < 2; ++h) {
      const int rbase = rowbase + ch * 32 + 16 * h + 8 * lh;
      float fa[8], fb[8];
      #pragma unroll
      for (int j = 0; j < 8; ++j) {
        const float* rp = F + (size_t)(rbase + j) * 128;
        fa[j] = rp[i0 + lr];
        fb[j] = rp[j0 + lr];
      }
      if (wj == 0) {
        #pragma unroll
        for (int j = 0; j < 8; ++j) svacc += fa[j];
      }
      uint4 av4, bv4;
      av4.x = pk2(fa[0], fa[1]); av4.y = pk2(fa[2], fa[3]);
      av4.z = pk2(fa[4], fa[5]); av4.w = pk2(fa[6], fa[7]);
      bv4.x = pk2(fb[0], fb[1]); bv4.y = pk2(fb[2], fb[3]);
      bv4.z = pk2(fb[4], fb[5]); bv4.w = pk2(fb[6], fb[7]);
      acc = __builtin_amdgcn_mfma_f32_32x32x16_bf16(
          __builtin_bit_cast(short8v, av4), __builtin_bit_cast(short8v, bv4),
          acc, 0, 0, 0);
    }
  }

  if (wj == 0) {
    svacc += __shfl_xor(svacc, 32);
    if (lane < 32) {
      if (PART) svpart[blockIdx.x * 128 + i0 + lr] = svacc;
      else      atomicAdd(&sv[i0 + lr], svacc);
    }
  }
  __syncthreads();
  if (tid < NCAT) blkcnt[blockIdx.x * NCAT + tid] = hl[tid];

  if (PART) {
    unsigned* gp = Gp16 + (size_t)blockIdx.x * 8192;
    #pragma unroll
    for (int t = 0; t < 8; ++t) {
      const int rowe = ((2 * t) & 3) + 8 * (t >> 1) + 4 * lh;   // even row of pair
      gp[((i0 + rowe) >> 1) * 128 + j0 + lr] = pk2(acc[2 * t], acc[2 * t + 1]);
    }
  } else {
    #pragma unroll
    for (int reg = 0; reg < 16; ++reg) {
      const int row = (reg & 3) + 8 * (reg >> 2) + 4 * lh;
      atomicAdd(&Gdst[(i0 + row) * 128 + j0 + lr], acc[reg]);
    }
  }
}

// ---------------------------------------------------------------------------
// K2 (fused): b<64 G-reduce (bf16 pairs, 2 threads/elem half-split + shfl);
// b==64 sv-reduce; b==65 prefix sums over blkcnt -> offs + counts.
// grid 66 x 256.
// ---------------------------------------------------------------------------
__global__ __launch_bounds__(256) void k_mid(
    const unsigned* __restrict__ Gp16, const float* __restrict__ svpart,
    const int* __restrict__ blkcnt, float* __restrict__ G,
    float* __restrict__ sv, int* __restrict__ offs,
    int* __restrict__ counts, int doRed)
{
  __shared__ int ps[16][16], ps2[16][16], tot[16], catbase[16];
  const int b = blockIdx.x, tid = threadIdx.x;
  if (b < 64) {
    if (!doRed) return;
    const int e = b * 128 + (tid >> 1);    // pair index 0..8191
    const int half = tid & 1;
    float lo = 0.f, hi = 0.f;
    #pragma unroll 4
    for (int p = half * 128; p < half * 128 + 128; ++p) {
      const unsigned u = Gp16[(size_t)p * 8192 + e];
      lo += bf2f((unsigned short)(u & 0xffffu));
      hi += bf2f((unsigned short)(u >> 16));
    }
    lo += __shfl_xor(lo, 1);
    hi += __shfl_xor(hi, 1);
    if (half == 0) {
      const int pr = e >> 7, col = e & 127;
      G[(2 * pr) * 128 + col]     = lo;
      G[(2 * pr + 1) * 128 + col] = hi;
    }
  } else if (b == 64) {
    if (!doRed) return;
    if (tid < 128) {
      float s = 0.f;
      #pragma unroll 8
      for (int p = 0; p < 256; ++p) s += svpart[p * 128 + tid];
      sv[tid] = s;
    }
  } else {
    const int part = tid >> 4, cat = tid & 15;
    int v[16]; int s = 0;
    #pragma unroll
    for (int i = 0; i < 16; ++i) { v[i] = s; s += blkcnt[(part * 16 + i) * 16 + cat]; }
    ps[part][cat] = s;
    __syncthreads();
    if (part == 0) {
      int a = 0;
      #pragma unroll
      for (int p = 0; p < 16; ++p) { ps2[p][cat] = a; a += ps[p][cat]; }
      tot[cat] = a; counts[cat] = a;
    }
    __syncthreads();
    if (tid == 0) {
      int a = 0;
      #pragma unroll
      for (int c = 0; c < 16; ++c) { catbase[c] = a; a += tot[c]; }
    }
    __syncthreads();
    const int base = catbase[cat] + ps2[part][cat];
    #pragma unroll
    for (int i = 0; i < 16; ++i) offs[(part * 16 + i) * 16 + cat] = base + v[i];
  }
}

// ---------------------------------------------------------------------------
// K3 (fused): b<256 scatter (rowidx + posidx, atomic-free, deterministic);
// b>=256 BN params from Gram. grid 384 x 256.
// ---------------------------------------------------------------------------
__global__ __launch_bounds__(256) void k_prep(
    const int* __restrict__ lab, const int* __restrict__ offs,
    const float* __restrict__ G, const float* __restrict__ sv,
    const float* __restrict__ W1, const float* __restrict__ gamma,
    const float* __restrict__ beta,
    int* __restrict__ rowidx, int* __restrict__ posidx,
    float* __restrict__ scale, float* __restrict__ shiftv)
{
  __shared__ float Gl[128][133];
  __shared__ float Wl[128][16];
  __shared__ float redq[16][16];
  __shared__ float redm[16][16];
  __shared__ int wc[4][NCAT];
  const int b = blockIdx.x, tid = threadIdx.x;
  if (b < 256) {
    const int wid = tid >> 6, lane = tid & 63;
    const int n = b * 256 + tid;
    const int c = lab[n];
    const unsigned long long lanebit = 1ull << lane;
    int myrank = 0;
    #pragma unroll
    for (int cc = 0; cc < NCAT; ++cc) {
      unsigned long long m = __ballot(c == cc);
      if (lane == 0) wc[wid][cc] = (int)__popcll(m);
      if (c == cc) myrank = (int)__popcll(m & (lanebit - 1));
    }
    __syncthreads();
    int base = 0;
    #pragma unroll
    for (int w = 0; w < 4; ++w)
      if (w < wid) base += wc[w][c];
    const int slot = offs[b * NCAT + c] + base + myrank;
    rowidx[slot] = n;
    posidx[n] = slot;
  } else {
    const int jb = (b - 256) * 16;
    for (int i = tid; i < 16384; i += 256) Gl[i >> 7][i & 127] = G[i];
    for (int i = tid; i < 2048; i += 256) {
      int k = i >> 4, col = i & 15;
      Wl[k][col] = W1[(size_t)k * 2048 + jb + col];
    }
    __syncthreads();
    const int col = tid & 15, part = tid >> 4;
    float msq = 0.f, mean = 0.f;
    for (int ii = 0; ii < 8; ++ii) {
      const int i = part * 8 + ii;
      const float wi = Wl[i][col];
      float inner = 0.f;
      #pragma unroll 8
      for (int k = 0; k < 128; ++k) inner = fmaf(Gl[i][k], Wl[k][col], inner);
      msq = fmaf(wi, inner, msq);
    }
    #pragma unroll
    for (int kk = 0; kk < 8; ++kk) {
      const int k = part * 8 + kk;
      mean = fmaf(sv[k], Wl[k][col], mean);
    }
    redq[part][col] = msq;
    redm[part][col] = mean;
    __syncthreads();
    if (tid < 16) {
      float q = 0.f, m = 0.f;
      #pragma unroll
      for (int p = 0; p < 16; ++p) { q += redq[p][tid]; m += redm[p][tid]; }
      m *= (1.f / 65536.f);
      q *= (1.f / 65536.f);
      float var = q - m * m;
      float sc = gamma[jb + tid] * rsqrtf(var + 1e-5f);
      scale[jb + tid] = sc;
      shiftv[jb + tid] = beta[jb + tid] - m * sc;
    }
  }
}

// ---------------------------------------------------------------------------
// K4: category-major MFMA main, in-kernel row-cooperative gather, and a
// ct-OUTER compute loop with fused per-ct epilogue partials: only ONE 4-VGPR
// acc live at a time (R14/R16's 8-acc version spilled to scratch at the
// 128-VGPR cap -> 54 MB phantom WRITE). launch_bounds(512,4): cap 128,
// 2 blocks/CU, 16 waves/CU. Math byte-identical to R16.
// ---------------------------------------------------------------------------
__global__ __launch_bounds__(512, 4) void k_main_g(
    const float* __restrict__ F, const unsigned short* __restrict__ Wlb,
    const float* __restrict__ W2p, const float* __restrict__ bias,
    const float* __restrict__ scale, const float* __restrict__ shiftv,
    const int* __restrict__ counts, const int* __restrict__ rowidx,
    float* __restrict__ tmp8)
{
  __shared__ __attribute__((aligned(16))) unsigned short Wl[16384];    // 32 KB
  __shared__ __attribute__((aligned(16))) unsigned short Flds[16384];  // 32 KB
  const int tid = threadIdx.x;
  const int cat = (int)blockIdx.x >> 5;
  const int blk = (int)blockIdx.x & (BCAT - 1);
  const int wid = tid >> 6, lane = tid & 63;
  const int lrow = lane & 15, lhi = lane >> 4;

  int off = 0, cnt = 0;
  #pragma unroll
  for (int t = 0; t < NCAT; ++t) {
    int cv = counts[t];
    if (t < cat) off += cv;
    if (t == cat) cnt = cv;
  }
  const int chunk = (cnt + BCAT - 1) / BCAT;
  const int start = off + blk * chunk;
  const int end = min(start + chunk, off + cnt);

  // stage this category's W tile into LDS (coalesced)
  {
    const uint4* src = (const uint4*)(Wlb + (size_t)cat * 16384);
    uint4* dst = (uint4*)Wl;
    for (int i = tid; i < 2048; i += 512) dst[i] = src[i];
  }
  if (start >= end) return;   // block-uniform: safe (no barrier crossed yet)

  float sc_r[8], sh_r[8];
  #pragma unroll
  for (int ct = 0; ct < 8; ++ct) {
    sc_r[ct] = scale[cat * 128 + ct * 16 + lrow];
    sh_r[ct] = shiftv[cat * 128 + ct * 16 + lrow];
  }
  float bi[6];
  #pragma unroll
  for (int s = 0; s < 6; ++s) bi[s] = bias[s];

  const int rsub = tid >> 5, t5 = tid & 31;   // 16 rows in flight, 32 lanes/row

  for (int w0 = start; w0 < end; w0 += 128) {
    const int nrows = min(128, end - w0);
    __syncthreads();   // Wl ready (1st iter) / previous window's readers done
    // gather + convert 128 rows into swizzled LDS
    #pragma unroll
    for (int i = 0; i < 8; ++i) {
      const int rl = i * 16 + rsub;                      // 0..127
      const int rsrc = rowidx[w0 + min(rl, nrows - 1)];  // broadcast per half-wave
      const float4 v = *(const float4*)(F + (size_t)rsrc * 128 + t5 * 4);
      uint2 pk;
      pk.x = pk2(v.x, v.y);
      pk.y = pk2(v.z, v.w);
      *(uint2*)((char*)Flds + rl * 256 + ((t5 * 8) ^ ((rl & 7) << 4))) = pk;
    }
    __syncthreads();   // Flds ready

    const int q0 = w0 + wid * 16;
    if (q0 < end) {
      const int lq = min(q0 + lrow, w0 + nrows - 1) - w0;   // local A row
      short8v av[4];
      #pragma unroll
      for (int ks = 0; ks < 4; ++ks) {
        const int co = (ks * 64 + lhi * 16) ^ ((lq & 7) << 4);
        av[ks] = *(const short8v*)((const char*)Flds + lq * 256 + co);
      }

      // ct-outer: one acc live at a time, consumed immediately
      float p[4][6];
      #pragma unroll
      for (int j = 0; j < 4; ++j)
        #pragma unroll
        for (int s = 0; s < 6; ++s) p[j][s] = 0.f;

      #pragma unroll
      for (int ct = 0; ct < 8; ++ct) {
        float4v acc = (float4v){0.f, 0.f, 0.f, 0.f};
        #pragma unroll
        for (int ks = 0; ks < 4; ++ks) {
          const short8v bv = *(const short8v*)(Wl + ((ks * 8 + ct) * 64 + lane) * 8);
          acc = __builtin_amdgcn_mfma_f32_16x16x32_bf16(av[ks], bv, acc, 0, 0, 0);
        }
        const int c = ct * 16 + lrow;
        const float s_ = sc_r[ct], h_ = sh_r[ct];
        const float4* w2p4 = (const float4*)(W2p + ((size_t)cat * 128 + c) * 8);
        const float4 wa = w2p4[0];
        const float4 wb4 = w2p4[1];
        const float w2v[6] = {wa.x, wa.y, wa.z, wa.w, wb4.x, wb4.y};
        #pragma unroll
        for (int j = 0; j < 4; ++j) {
          float a = acc[j] * s_ + h_;
          a = (a >= 0.f) ? a : 0.2f * a;
          #pragma unroll
          for (int s = 0; s < 6; ++s) p[j][s] = fmaf(a, w2v[s], p[j][s]);
        }
      }

      // reduce-scatter over the 16-lane group: lvl1/2 keep j == lrow&3
      const bool b1 = (lrow & 1) != 0;
      const bool b2 = (lrow & 2) != 0;
      float q[2][6], r[6];
      #pragma unroll
      for (int t = 0; t < 2; ++t)
        #pragma unroll
        for (int s = 0; s < 6; ++s) {
          float snd = b1 ? p[2 * t][s] : p[2 * t + 1][s];
          float kp  = b1 ? p[2 * t + 1][s] : p[2 * t][s];
          q[t][s] = kp + __shfl_xor(snd, 1);
        }
      #pragma unroll
      for (int s = 0; s < 6; ++s) {
        float snd = b2 ? q[0][s] : q[1][s];
        float kp  = b2 ? q[1][s] : q[0][s];
        r[s] = kp + __shfl_xor(snd, 2);
      }
      #pragma unroll
      for (int s = 0; s < 6; ++s) r[s] += __shfl_xor(r[s], 4);
      #pragma unroll
      for (int s = 0; s < 6; ++s) r[s] += __shfl_xor(r[s], 8);

      const int jj = lrow & 3, sb = lrow >> 2;
      const int qrow = min(q0 + 4 * lhi + jj, end - 1);   // slot position
      float pj[6];
      #pragma unroll
      for (int s = 0; s < 6; ++s) pj[s] = r[s] + bi[s];
      float mx = fmaxf(fmaxf(fmaxf(pj[0], pj[1]), fmaxf(pj[2], pj[3])), fmaxf(pj[4], pj[5]));
      float e = __expf(pj[0] - mx) + __expf(pj[1] - mx) + __expf(pj[2] - mx)
              + __expf(pj[3] - mx) + __expf(pj[4] - mx) + __expf(pj[5] - mx);
      float lse = mx + __logf(e);

      float4* trec = (float4*)(tmp8 + (size_t)qrow * 8);
      if (sb == 0) {
        float4 v0; v0.x = pj[0] - lse; v0.y = pj[1] - lse;
        v0.z = pj[2] - lse; v0.w = pj[3] - lse;
        trec[0] = v0;
      } else if (sb == 1) {
        float4 v1; v1.x = pj[4] - lse; v1.y = pj[5] - lse;
        v1.z = 0.f; v1.w = 0.f;
        trec[1] = v1;
      }
    }
  }
}

// ---------------------------------------------------------------------------
// K5: permute records -> dense output in OUTPUT order (fully coalesced
// full-line stores, no RMW). grid 6912 x 256 (one float2/thread).
// ---------------------------------------------------------------------------
__global__ __launch_bounds__(256) void k_out(
    const float* __restrict__ tmp8, const int* __restrict__ lab,
    const int* __restrict__ posidx, float* __restrict__ out)
{
  const int i2 = blockIdx.x * 256 + threadIdx.x;  // 0 .. 65536*27
  const int n = i2 / 27;
  const int j2 = i2 - n * 27;
  const int c = lab[n];
  const int shc = c_shift[c], lnc = c_len[c];
  const float* rec = tmp8 + (size_t)posidx[n] * 8;
  const int s0 = 2 * j2 - shc;
  float2 v; v.x = 0.f; v.y = 0.f;
  if (s0 >= 0 && s0 < lnc)         v.x = rec[s0];
  if (s0 + 1 >= 0 && s0 + 1 < lnc) v.y = rec[s0 + 1];
  ((float2*)out)[i2] = v;
}

// ---------------------------------------------------------------------------
// Host launcher — 5 launches (both paths share everything but k_stats mode).
// ---------------------------------------------------------------------------
extern "C" void kernel_launch(void* const* d_in, const int* in_sizes, int n_in,
                              void* d_out, int out_size, void* d_ws, size_t ws_size,
                              hipStream_t stream) {
  const float* F     = (const float*)d_in[0];
  const float* W1    = (const float*)d_in[1];
  const float* gamma = (const float*)d_in[2];
  const float* beta  = (const float*)d_in[3];
  const float* W2    = (const float*)d_in[4];
  const float* bias  = (const float*)d_in[5];
  const int*   lab   = (const int*)d_in[6];
  float* out = (float*)d_out;

  char* ws = (char*)d_ws;
  float* sv      = (float*)(ws + 0);
  int*   counts  = (int*)(ws + 512);
  int*   blkcnt  = (int*)(ws + 576);
  int*   offs    = (int*)(ws + 16960);
  float* scale   = (float*)(ws + 33344);
  float* shiftv  = (float*)(ws + 41536);
  float* G       = (float*)(ws + 49728);
  int*   rowidx  = (int*)(ws + 115264);
  int*   posidx  = (int*)(ws + 377408);
  unsigned short* Wlb = (unsigned short*)(ws + 639552);
  float* W2p     = (float*)(ws + 1163840);
  float* tmp8    = (float*)(ws + 1229376);
  unsigned* Gp16 = (unsigned*)(ws + 3326528);
  float* svpart  = (float*)(ws + 11715136);

  const size_t need = 11846208;  // ~11.85 MB
  const int fast = (ws_size >= need) ? 1 : 0;
  if (fast) {
    hipLaunchKernelGGL(k_stats_m<true>, dim3(272), dim3(1024), 0, stream,
                       F, W1, W2, lab, G, Gp16, sv, svpart, blkcnt, Wlb, W2p);
  } else {
    hipMemsetAsync(d_ws, 0, 115264, stream);  // sv + G (+counts/blkcnt harmless)
    hipLaunchKernelGGL(k_stats_m<false>, dim3(272), dim3(1024), 0, stream,
                       F, W1, W2, lab, G, Gp16, sv, svpart, blkcnt, Wlb, W2p);
  }
  hipLaunchKernelGGL(k_mid, dim3(66), dim3(256), 0, stream,
                     Gp16, svpart, blkcnt, G, sv, offs, counts, fast);
  hipLaunchKernelGGL(k_prep, dim3(384), dim3(256), 0, stream,
                     lab, offs, G, sv, W1, gamma, beta, rowidx, posidx, scale, shiftv);
  hipLaunchKernelGGL(k_main_g, dim3(NCAT * BCAT), dim3(512), 0, stream,
                     F, Wlb, W2p, bias, scale, shiftv, counts, rowidx, tmp8);
  hipLaunchKernelGGL(k_out, dim3(6912), dim3(256), 0, stream,
                     tmp8, lab, posidx, out);
}